// Round 1
// baseline (938.667 us; speedup 1.0000x reference)
//
#include <hip/hip_runtime.h>
#include <cstddef>

#define NN 50000
#define EE 800000
#define ET_ (EE + NN)

__device__ __forceinline__ float lrelu_(float x) { return x > 0.f ? x : 0.2f * x; }
__device__ __forceinline__ float elu_(float x)   { return x > 0.f ? x : (__expf(x) - 1.f); }

// ---------------- CSR build ----------------

__global__ __launch_bounds__(256) void zero_k(int* p, int n) {
    int i = blockIdx.x * blockDim.x + threadIdx.x;
    if (i < n) p[i] = 0;
}

__global__ __launch_bounds__(256) void degree_k(const int* __restrict__ ei, int* __restrict__ deg) {
    int e = blockIdx.x * blockDim.x + threadIdx.x;
    if (e >= ET_) return;
    int d = (e < EE) ? ei[EE + e] : (e - EE);
    atomicAdd(&deg[d], 1);
}

__global__ __launch_bounds__(1024) void scan_k(const int* __restrict__ deg, int* __restrict__ rowptr, int n) {
    __shared__ int sbuf[1024];
    __shared__ int carry_s;
    int tid = threadIdx.x;
    if (tid == 0) carry_s = 0;
    __syncthreads();
    for (int base = 0; base < n; base += 1024) {
        int idx = base + tid;
        int v = (idx < n) ? deg[idx] : 0;
        sbuf[tid] = v;
        __syncthreads();
        // Hillis-Steele inclusive scan
        for (int off = 1; off < 1024; off <<= 1) {
            int t = (tid >= off) ? sbuf[tid - off] : 0;
            __syncthreads();
            sbuf[tid] += t;
            __syncthreads();
        }
        int incl = sbuf[tid];
        int carry = carry_s;
        if (idx < n) rowptr[idx] = carry + incl - v;   // exclusive
        __syncthreads();
        if (tid == 1023) carry_s = carry + sbuf[1023];
        __syncthreads();
    }
    if (tid == 0) rowptr[n] = carry_s;
}

__global__ __launch_bounds__(256) void scatter_k(const int* __restrict__ ei,
                                                 const int* __restrict__ rowptr,
                                                 int* __restrict__ cursor,
                                                 int* __restrict__ csr_src) {
    int e = blockIdx.x * blockDim.x + threadIdx.x;
    if (e >= ET_) return;
    int s, d;
    if (e < EE) { s = ei[e]; d = ei[EE + e]; } else { s = e - EE; d = e - EE; }
    int pos = atomicAdd(&cursor[d], 1);
    csr_src[rowptr[d] + pos] = s;
}

// ---------------- fp32 tiled GEMM: C[M,Nn] = A[M,K] @ W[K,Nn] (+bias) ----------------

__global__ __launch_bounds__(256) void gemm64(const float* __restrict__ A,
                                              const float* __restrict__ W,
                                              const float* __restrict__ bias,
                                              float* __restrict__ C,
                                              int M, int Nn, int K) {
    __shared__ float As[16][64];
    __shared__ float Ws[16][64];
    int tid = threadIdx.x;
    int bm = blockIdx.x * 64, bn = blockIdx.y * 64;
    int tm = tid >> 4, tn = tid & 15;
    float acc[4][4] = {};

    int la_m = tid >> 2;          // 0..63
    int la_k = (tid & 3) * 4;     // 0,4,8,12
    int lw_k = tid >> 4;          // 0..15
    int lw_n = (tid & 15) * 4;    // 0..60

    for (int k0 = 0; k0 < K; k0 += 16) {
        int am = bm + la_m;
        float4 av = make_float4(0.f, 0.f, 0.f, 0.f);
        if (am < M) av = *(const float4*)(A + (size_t)am * K + k0 + la_k);
        As[la_k + 0][la_m] = av.x;
        As[la_k + 1][la_m] = av.y;
        As[la_k + 2][la_m] = av.z;
        As[la_k + 3][la_m] = av.w;
        float4 wv = *(const float4*)(W + (size_t)(k0 + lw_k) * Nn + bn + lw_n);
        *(float4*)(&Ws[lw_k][lw_n]) = wv;
        __syncthreads();
#pragma unroll
        for (int kk = 0; kk < 16; ++kk) {
            float4 a = *(const float4*)(&As[kk][tm * 4]);
            float4 b = *(const float4*)(&Ws[kk][tn * 4]);
            acc[0][0] += a.x * b.x; acc[0][1] += a.x * b.y; acc[0][2] += a.x * b.z; acc[0][3] += a.x * b.w;
            acc[1][0] += a.y * b.x; acc[1][1] += a.y * b.y; acc[1][2] += a.y * b.z; acc[1][3] += a.y * b.w;
            acc[2][0] += a.z * b.x; acc[2][1] += a.z * b.y; acc[2][2] += a.z * b.z; acc[2][3] += a.z * b.w;
            acc[3][0] += a.w * b.x; acc[3][1] += a.w * b.y; acc[3][2] += a.w * b.z; acc[3][3] += a.w * b.w;
        }
        __syncthreads();
    }
#pragma unroll
    for (int i = 0; i < 4; ++i) {
        int m = bm + tm * 4 + i;
        if (m >= M) continue;
        int nc = bn + tn * 4;
        float4 o;
        o.x = acc[i][0]; o.y = acc[i][1]; o.z = acc[i][2]; o.w = acc[i][3];
        if (bias) {
            o.x += bias[nc + 0]; o.y += bias[nc + 1]; o.z += bias[nc + 2]; o.w += bias[nc + 3];
        }
        *(float4*)(C + (size_t)m * Nn + nc) = o;
    }
}

// ---------------- attention prep: a_s/a_d per node per head ----------------

__global__ __launch_bounds__(256) void attn_prep(const float* __restrict__ XL,
                                                 const float* __restrict__ cas,
                                                 const float* __restrict__ cad,
                                                 float* __restrict__ AS,
                                                 float* __restrict__ AD, int n_nodes) {
    int n = (blockIdx.x * blockDim.x + threadIdx.x) >> 6;
    int lane = threadIdx.x & 63;
    if (n >= n_nodes) return;
    float4 xv = *(const float4*)(XL + (size_t)n * 256 + lane * 4);
    float4 sv = *(const float4*)(cas + lane * 4);
    float4 dv = *(const float4*)(cad + lane * 4);
    float ps = xv.x * sv.x + xv.y * sv.y + xv.z * sv.z + xv.w * sv.w;
    float pd = xv.x * dv.x + xv.y * dv.y + xv.z * dv.z + xv.w * dv.w;
#pragma unroll
    for (int off = 1; off < 16; off <<= 1) {
        ps += __shfl_xor(ps, off);
        pd += __shfl_xor(pd, off);
    }
    if ((lane & 15) == 0) {
        AS[n * 4 + (lane >> 4)] = ps;
        AD[n * 4 + (lane >> 4)] = pd;
    }
}

// ---------------- GAT aggregation (layers 0/1), wave per node ----------------
// H (inout) contains the linear branch (x@lW+lb); writes elu(gat + cb + H).

__global__ __launch_bounds__(256) void gat_agg(const float* __restrict__ XL,
                                               const float* __restrict__ AS,
                                               const float* __restrict__ AD,
                                               const int* __restrict__ rowptr,
                                               const int* __restrict__ csr_src,
                                               const float* __restrict__ cb,
                                               float* __restrict__ H, int n_nodes) {
    int n = (blockIdx.x * blockDim.x + threadIdx.x) >> 6;
    int lane = threadIdx.x & 63;
    if (n >= n_nodes) return;
    int rs = rowptr[n], re = rowptr[n + 1];
    float4 ad4 = *(const float4*)(AD + n * 4);

    // pass A: per-head max over incoming edges (lane-parallel)
    float m0 = -1e30f, m1 = -1e30f, m2 = -1e30f, m3 = -1e30f;
    for (int i = rs + lane; i < re; i += 64) {
        int s = csr_src[i];
        float4 as = *(const float4*)(AS + s * 4);
        m0 = fmaxf(m0, lrelu_(as.x + ad4.x));
        m1 = fmaxf(m1, lrelu_(as.y + ad4.y));
        m2 = fmaxf(m2, lrelu_(as.z + ad4.z));
        m3 = fmaxf(m3, lrelu_(as.w + ad4.w));
    }
#pragma unroll
    for (int off = 32; off > 0; off >>= 1) {
        m0 = fmaxf(m0, __shfl_xor(m0, off));
        m1 = fmaxf(m1, __shfl_xor(m1, off));
        m2 = fmaxf(m2, __shfl_xor(m2, off));
        m3 = fmaxf(m3, __shfl_xor(m3, off));
    }

    // per-lane head selection (lane owns channels [4*lane,4*lane+4), head = lane>>4)
    int h = lane >> 4;
    float mh  = (h == 0) ? m0 : (h == 1) ? m1 : (h == 2) ? m2 : m3;
    float adh = (h == 0) ? ad4.x : (h == 1) ? ad4.y : (h == 2) ? ad4.z : ad4.w;

    // pass C: serial over edges; accumulate ex*x and ex (denominator)
    float4 acc = make_float4(0.f, 0.f, 0.f, 0.f);
    float den = 0.f;
    for (int i = rs; i < re; ++i) {
        int s = csr_src[i];
        float asv = AS[s * 4 + h];
        float ex = __expf(lrelu_(asv + adh) - mh);
        float4 xv = *(const float4*)(XL + (size_t)s * 256 + lane * 4);
        den += ex;
        acc.x += ex * xv.x; acc.y += ex * xv.y; acc.z += ex * xv.z; acc.w += ex * xv.w;
    }
    float inv = 1.f / (den + 1e-16f);

    size_t o = (size_t)n * 256 + lane * 4;
    float4 hv = *(const float4*)(H + o);
    float4 cbv = *(const float4*)(cb + lane * 4);
    hv.x = elu_(acc.x * inv + cbv.x + hv.x);
    hv.y = elu_(acc.y * inv + cbv.y + hv.y);
    hv.z = elu_(acc.z * inv + cbv.z + hv.z);
    hv.w = elu_(acc.w * inv + cbv.w + hv.w);
    *(float4*)(H + o) = hv;
}

// ---------------- layer 2 projections: xl2[N,4] = H@cW2, lin2[N] = H@lW2+lb2 ----------------

__global__ __launch_bounds__(256) void l2_prep(const float* __restrict__ Hin,
                                               const float* __restrict__ cW2,
                                               const float* __restrict__ lW2,
                                               const float* __restrict__ lb2,
                                               float* __restrict__ XL2,
                                               float* __restrict__ LIN2, int n_nodes) {
    int n = (blockIdx.x * blockDim.x + threadIdx.x) >> 6;
    int lane = threadIdx.x & 63;
    if (n >= n_nodes) return;
    float4 hv = *(const float4*)(Hin + (size_t)n * 256 + lane * 4);
    float hk0 = hv.x, hk1 = hv.y, hk2 = hv.z, hk3 = hv.w;
    float a0 = 0.f, a1 = 0.f, a2 = 0.f, a3 = 0.f, al = 0.f;
    int k = lane * 4;
    float4 w0 = *(const float4*)(cW2 + (k + 0) * 4);
    float4 w1 = *(const float4*)(cW2 + (k + 1) * 4);
    float4 w2 = *(const float4*)(cW2 + (k + 2) * 4);
    float4 w3 = *(const float4*)(cW2 + (k + 3) * 4);
    a0 = hk0 * w0.x + hk1 * w1.x + hk2 * w2.x + hk3 * w3.x;
    a1 = hk0 * w0.y + hk1 * w1.y + hk2 * w2.y + hk3 * w3.y;
    a2 = hk0 * w0.z + hk1 * w1.z + hk2 * w2.z + hk3 * w3.z;
    a3 = hk0 * w0.w + hk1 * w1.w + hk2 * w2.w + hk3 * w3.w;
    float4 lw = make_float4(lW2[k], lW2[k + 1], lW2[k + 2], lW2[k + 3]);
    al = hk0 * lw.x + hk1 * lw.y + hk2 * lw.z + hk3 * lw.w;
#pragma unroll
    for (int off = 32; off > 0; off >>= 1) {
        a0 += __shfl_xor(a0, off); a1 += __shfl_xor(a1, off);
        a2 += __shfl_xor(a2, off); a3 += __shfl_xor(a3, off);
        al += __shfl_xor(al, off);
    }
    if (lane == 0) {
        float4 o = make_float4(a0, a1, a2, a3);
        *(float4*)(XL2 + n * 4) = o;
        LIN2[n] = al + lb2[0];
    }
}

// ---------------- layer 2 aggregation (mean over heads) -> out ----------------

__global__ __launch_bounds__(256) void l2_agg(const float* __restrict__ XL2,
                                              const float* __restrict__ LIN2,
                                              const float* __restrict__ cas2,
                                              const float* __restrict__ cad2,
                                              const float* __restrict__ cb2,
                                              const int* __restrict__ rowptr,
                                              const int* __restrict__ csr_src,
                                              float* __restrict__ out, int n_nodes) {
    int n = (blockIdx.x * blockDim.x + threadIdx.x) >> 6;
    int lane = threadIdx.x & 63;
    if (n >= n_nodes) return;
    int rs = rowptr[n], re = rowptr[n + 1];
    float4 xn = *(const float4*)(XL2 + n * 4);
    float cs0 = cas2[0], cs1 = cas2[1], cs2 = cas2[2], cs3 = cas2[3];
    float cd0 = cad2[0], cd1 = cad2[1], cd2 = cad2[2], cd3 = cad2[3];
    float ad0 = xn.x * cd0, ad1 = xn.y * cd1, ad2 = xn.z * cd2, ad3 = xn.w * cd3;

    float m0 = -1e30f, m1 = -1e30f, m2 = -1e30f, m3 = -1e30f;
    for (int i = rs + lane; i < re; i += 64) {
        int s = csr_src[i];
        float4 xs = *(const float4*)(XL2 + s * 4);
        m0 = fmaxf(m0, lrelu_(xs.x * cs0 + ad0));
        m1 = fmaxf(m1, lrelu_(xs.y * cs1 + ad1));
        m2 = fmaxf(m2, lrelu_(xs.z * cs2 + ad2));
        m3 = fmaxf(m3, lrelu_(xs.w * cs3 + ad3));
    }
#pragma unroll
    for (int off = 32; off > 0; off >>= 1) {
        m0 = fmaxf(m0, __shfl_xor(m0, off));
        m1 = fmaxf(m1, __shfl_xor(m1, off));
        m2 = fmaxf(m2, __shfl_xor(m2, off));
        m3 = fmaxf(m3, __shfl_xor(m3, off));
    }

    float d0 = 0.f, d1 = 0.f, d2 = 0.f, d3 = 0.f;
    float t0 = 0.f, t1 = 0.f, t2 = 0.f, t3 = 0.f;
    for (int i = rs + lane; i < re; i += 64) {
        int s = csr_src[i];
        float4 xs = *(const float4*)(XL2 + s * 4);
        float e0 = __expf(lrelu_(xs.x * cs0 + ad0) - m0);
        float e1 = __expf(lrelu_(xs.y * cs1 + ad1) - m1);
        float e2 = __expf(lrelu_(xs.z * cs2 + ad2) - m2);
        float e3 = __expf(lrelu_(xs.w * cs3 + ad3) - m3);
        d0 += e0; d1 += e1; d2 += e2; d3 += e3;
        t0 += e0 * xs.x; t1 += e1 * xs.y; t2 += e2 * xs.z; t3 += e3 * xs.w;
    }
#pragma unroll
    for (int off = 32; off > 0; off >>= 1) {
        d0 += __shfl_xor(d0, off); d1 += __shfl_xor(d1, off);
        d2 += __shfl_xor(d2, off); d3 += __shfl_xor(d3, off);
        t0 += __shfl_xor(t0, off); t1 += __shfl_xor(t1, off);
        t2 += __shfl_xor(t2, off); t3 += __shfl_xor(t3, off);
    }
    if (lane == 0) {
        float r = 0.25f * (t0 / (d0 + 1e-16f) + t1 / (d1 + 1e-16f) +
                           t2 / (d2 + 1e-16f) + t3 / (d3 + 1e-16f));
        out[n] = r + cb2[0] + LIN2[n];
    }
}

// ---------------- launch ----------------

extern "C" void kernel_launch(void* const* d_in, const int* in_sizes, int n_in,
                              void* d_out, int out_size, void* d_ws, size_t ws_size,
                              hipStream_t stream) {
    const float* x    = (const float*)d_in[0];
    const int*   ei   = (const int*)d_in[1];
    const float* cW0  = (const float*)d_in[3];
    const float* cas0 = (const float*)d_in[4];
    const float* cad0 = (const float*)d_in[5];
    const float* cb0  = (const float*)d_in[6];
    const float* lW0  = (const float*)d_in[7];
    const float* lb0  = (const float*)d_in[8];
    const float* cW1  = (const float*)d_in[9];
    const float* cas1 = (const float*)d_in[10];
    const float* cad1 = (const float*)d_in[11];
    const float* cb1  = (const float*)d_in[12];
    const float* lW1  = (const float*)d_in[13];
    const float* lb1  = (const float*)d_in[14];
    const float* cW2  = (const float*)d_in[15];
    const float* cas2 = (const float*)d_in[16];
    const float* cad2 = (const float*)d_in[17];
    const float* cb2  = (const float*)d_in[18];
    const float* lW2  = (const float*)d_in[19];
    const float* lb2  = (const float*)d_in[20];
    float* out = (float*)d_out;

    // workspace layout (~160.2 MB)
    float* XL   = (float*)d_ws;
    float* HA   = XL + (size_t)NN * 256;
    float* HB   = HA + (size_t)NN * 256;
    float* AS   = HB + (size_t)NN * 256;
    float* AD   = AS + (size_t)NN * 4;
    float* XL2  = AD + (size_t)NN * 4;
    float* LIN2 = XL2 + (size_t)NN * 4;
    int* deg     = (int*)(LIN2 + NN);
    int* cursor  = deg + NN;
    int* rowptr  = cursor + NN;
    int* csr_src = rowptr + (NN + 1);

    dim3 b256(256);
    dim3 gEdges((ET_ + 255) / 256);
    dim3 gNodesWave((NN + 3) / 4);       // wave-per-node kernels: 4 waves/block
    dim3 gemmGrid((NN + 63) / 64, 256 / 64);

    // CSR build
    zero_k<<<dim3((2 * NN + 255) / 256), b256, 0, stream>>>(deg, 2 * NN);
    degree_k<<<gEdges, b256, 0, stream>>>(ei, deg);
    scan_k<<<dim3(1), dim3(1024), 0, stream>>>(deg, rowptr, NN);
    scatter_k<<<gEdges, b256, 0, stream>>>(ei, rowptr, cursor, csr_src);

    // layer 0
    gemm64<<<gemmGrid, b256, 0, stream>>>(x, lW0, lb0, HA, NN, 256, 128);
    gemm64<<<gemmGrid, b256, 0, stream>>>(x, cW0, nullptr, XL, NN, 256, 128);
    attn_prep<<<gNodesWave, b256, 0, stream>>>(XL, cas0, cad0, AS, AD, NN);
    gat_agg<<<gNodesWave, b256, 0, stream>>>(XL, AS, AD, rowptr, csr_src, cb0, HA, NN);

    // layer 1
    gemm64<<<gemmGrid, b256, 0, stream>>>(HA, lW1, lb1, HB, NN, 256, 256);
    gemm64<<<gemmGrid, b256, 0, stream>>>(HA, cW1, nullptr, XL, NN, 256, 256);
    attn_prep<<<gNodesWave, b256, 0, stream>>>(XL, cas1, cad1, AS, AD, NN);
    gat_agg<<<gNodesWave, b256, 0, stream>>>(XL, AS, AD, rowptr, csr_src, cb1, HB, NN);

    // layer 2
    l2_prep<<<gNodesWave, b256, 0, stream>>>(HB, cW2, lW2, lb2, XL2, LIN2, NN);
    l2_agg<<<gNodesWave, b256, 0, stream>>>(XL2, LIN2, cas2, cad2, cb2, rowptr, csr_src, out, NN);
}

// Round 2
// 592.577 us; speedup vs baseline: 1.5840x; 1.5840x over previous
//
#include <hip/hip_runtime.h>
#include <cstddef>
#include <cstdint>

#define NN 50000
#define EE 800000
#define ET_ (EE + NN)

typedef __attribute__((ext_vector_type(8))) short bf16x8;
typedef __attribute__((ext_vector_type(4))) float f32x4;

__device__ __forceinline__ float lrelu_(float x) { return x > 0.f ? x : 0.2f * x; }
__device__ __forceinline__ float elu_(float x)   { return x > 0.f ? x : (__expf(x) - 1.f); }
__device__ __forceinline__ short f2bf(float f) {
    unsigned u = __float_as_uint(f);
    unsigned r = (u + 0x7fffu + ((u >> 16) & 1u)) >> 16;
    return (short)r;
}
__device__ __forceinline__ float bfu(unsigned u16v) { return __uint_as_float(u16v << 16); }

#define GL16(gp, lp) __builtin_amdgcn_global_load_lds( \
    (const __attribute__((address_space(1))) unsigned int*)(gp), \
    (__attribute__((address_space(3))) unsigned int*)(lp), 16, 0, 0)

// ---------------- CSR build ----------------

__global__ __launch_bounds__(256) void zero_k(int* p, int n) {
    int i = blockIdx.x * blockDim.x + threadIdx.x;
    if (i < n) p[i] = 0;
}

__global__ __launch_bounds__(256) void degree_k(const int* __restrict__ ei, int* __restrict__ deg) {
    int e = blockIdx.x * blockDim.x + threadIdx.x;
    if (e >= ET_) return;
    int d = (e < EE) ? ei[EE + e] : (e - EE);
    atomicAdd(&deg[d], 1);
}

__global__ __launch_bounds__(1024) void scan1(const int* __restrict__ deg, int* __restrict__ excl,
                                              int* __restrict__ bsum, int n) {
    __shared__ int s[1024];
    int tid = threadIdx.x;
    int gid = blockIdx.x * 1024 + tid;
    int v = (gid < n) ? deg[gid] : 0;
    s[tid] = v;
    __syncthreads();
    for (int off = 1; off < 1024; off <<= 1) {
        int t = (tid >= off) ? s[tid - off] : 0;
        __syncthreads();
        s[tid] += t;
        __syncthreads();
    }
    if (gid < n) excl[gid] = s[tid] - v;
    if (tid == 1023) bsum[blockIdx.x] = s[1023];
}

__global__ __launch_bounds__(64) void scan2(int* bsum, int nb) {
    int tid = threadIdx.x;
    int v = (tid < nb) ? bsum[tid] : 0;
    int s = v;
#pragma unroll
    for (int off = 1; off < 64; off <<= 1) {
        int t = __shfl_up(s, off);
        if (tid >= off) s += t;
    }
    if (tid < nb) bsum[tid] = s - v;   // exclusive
}

__global__ __launch_bounds__(256) void scan3(const int* __restrict__ excl, const int* __restrict__ bsum,
                                             int* __restrict__ rowptr, int n) {
    int i = blockIdx.x * blockDim.x + threadIdx.x;
    if (i < n) rowptr[i] = excl[i] + bsum[i >> 10];
    if (i == 0) rowptr[n] = ET_;
}

__global__ __launch_bounds__(256) void scatter_k(const int* __restrict__ ei,
                                                 const int* __restrict__ rowptr,
                                                 int* __restrict__ cursor,
                                                 int* __restrict__ csr_src) {
    int e = blockIdx.x * blockDim.x + threadIdx.x;
    if (e >= ET_) return;
    int s, d;
    if (e < EE) { s = ei[e]; d = ei[EE + e]; } else { s = e - EE; d = e - EE; }
    int pos = atomicAdd(&cursor[d], 1);
    csr_src[rowptr[d] + pos] = s;
}

// ---------------- dtype conversion / weight packing ----------------

__global__ __launch_bounds__(256) void f2bf_k(const float* __restrict__ src, short* __restrict__ dst, int n4) {
    int i = (blockIdx.x * blockDim.x + threadIdx.x) * 4;
    if (i >= n4) return;
    float4 v = *(const float4*)(src + i);
    short4 o;
    o.x = f2bf(v.x); o.y = f2bf(v.y); o.z = f2bf(v.z); o.w = f2bf(v.w);
    *(short4*)(dst + i) = o;
}

// Wt[n][k] bf16, n in [0,512): n<256 -> cW[k][n], else lW[k][n-256]
__global__ __launch_bounds__(256) void prep_w(const float* __restrict__ cW, const float* __restrict__ lW,
                                              short* __restrict__ Wt, int K) {
    int idx = blockIdx.x * blockDim.x + threadIdx.x;
    if (idx >= 512 * K) return;
    int n = idx / K, k = idx - n * K;
    float v = (n < 256) ? cW[k * 256 + n] : lW[k * 256 + (n - 256)];
    Wt[idx] = f2bf(v);
}

// ---------------- bf16 MFMA GEMM: out[M,512] = A[M,K] @ Wt^T ----------------
// cols 0..255 -> XLb (bf16, no bias); cols 256..511 -> Hlin (fp32, +biasLin)

__global__ __launch_bounds__(256) void gemm_bf16(const short* __restrict__ A,
                                                 const short* __restrict__ Wt,
                                                 const float* __restrict__ biasLin,
                                                 short* __restrict__ XLb,
                                                 float* __restrict__ Hlin,
                                                 int M, int K) {
    __shared__ short As[128 * 32];
    __shared__ short Bs[128 * 32];
    const int tid = threadIdx.x;
    const int lane = tid & 63;
    const int wid = tid >> 6;
    const int bm = blockIdx.x * 128;
    const int col0 = blockIdx.y * 128;
    const int wr = wid >> 1, wc = wid & 1;

    f32x4 acc[4][4];
#pragma unroll
    for (int i = 0; i < 4; ++i)
#pragma unroll
        for (int j = 0; j < 4; ++j) acc[i][j] = (f32x4){0.f, 0.f, 0.f, 0.f};

    const int lrow = lane & 15, lk = lane >> 4;

    for (int k0 = 0; k0 < K; k0 += 32) {
#pragma unroll
        for (int it = 0; it < 2; ++it) {
            const int flat = tid + it * 256;
            const int row = flat >> 2, slot = flat & 3;
            const int ss = slot ^ (row & 3);      // pre-swizzled source chunk
            int ar = bm + row; ar = (ar < M) ? ar : (M - 1);
            GL16(A + (size_t)ar * K + k0 + ss * 8, As + flat * 8);
            GL16(Wt + (size_t)(col0 + row) * K + k0 + ss * 8, Bs + flat * 8);
        }
        __syncthreads();
        bf16x8 af[4], bfr[4];
#pragma unroll
        for (int mi = 0; mi < 4; ++mi) {
            const int r = wr * 64 + mi * 16 + lrow;
            af[mi] = *(const bf16x8*)(As + (r * 4 + (lk ^ (r & 3))) * 8);
        }
#pragma unroll
        for (int ni = 0; ni < 4; ++ni) {
            const int c = wc * 64 + ni * 16 + lrow;
            bfr[ni] = *(const bf16x8*)(Bs + (c * 4 + (lk ^ (c & 3))) * 8);
        }
#pragma unroll
        for (int mi = 0; mi < 4; ++mi)
#pragma unroll
            for (int ni = 0; ni < 4; ++ni)
                acc[mi][ni] = __builtin_amdgcn_mfma_f32_16x16x32_bf16(af[mi], bfr[ni], acc[mi][ni], 0, 0, 0);
        __syncthreads();
    }

    const int lrow4 = (lane >> 4) * 4;
    const bool isLin = (col0 >= 256);
#pragma unroll
    for (int mi = 0; mi < 4; ++mi) {
#pragma unroll
        for (int ni = 0; ni < 4; ++ni) {
            const int col = col0 + wc * 64 + ni * 16 + (lane & 15);
#pragma unroll
            for (int rr = 0; rr < 4; ++rr) {
                const int grow = bm + wr * 64 + mi * 16 + lrow4 + rr;
                if (grow < M) {
                    float v = acc[mi][ni][rr];
                    if (isLin) {
                        const int c = col - 256;
                        Hlin[(size_t)grow * 256 + c] = v + biasLin[c];
                    } else {
                        XLb[(size_t)grow * 256 + col] = f2bf(v);
                    }
                }
            }
        }
    }
}

// ---------------- attention prep: a_s/a_d per node per head (bf16 xl) ----------------

__global__ __launch_bounds__(256) void attn_prep(const short* __restrict__ XLb,
                                                 const float* __restrict__ cas,
                                                 const float* __restrict__ cad,
                                                 float* __restrict__ AS,
                                                 float* __restrict__ AD, int n_nodes) {
    int n = (blockIdx.x * blockDim.x + threadIdx.x) >> 6;
    int lane = threadIdx.x & 63;
    if (n >= n_nodes) return;
    uint2 q = *(const uint2*)(XLb + (size_t)n * 256 + lane * 4);
    float x0 = bfu(q.x & 0xffff), x1 = bfu(q.x >> 16);
    float x2 = bfu(q.y & 0xffff), x3 = bfu(q.y >> 16);
    float4 sv = *(const float4*)(cas + lane * 4);
    float4 dv = *(const float4*)(cad + lane * 4);
    float ps = x0 * sv.x + x1 * sv.y + x2 * sv.z + x3 * sv.w;
    float pd = x0 * dv.x + x1 * dv.y + x2 * dv.z + x3 * dv.w;
#pragma unroll
    for (int off = 1; off < 16; off <<= 1) {
        ps += __shfl_xor(ps, off);
        pd += __shfl_xor(pd, off);
    }
    if ((lane & 15) == 0) {
        AS[n * 4 + (lane >> 4)] = ps;
        AD[n * 4 + (lane >> 4)] = pd;
    }
}

// ---------------- GAT aggregation (layers 0/1), wave per node ----------------

__global__ __launch_bounds__(256) void gat_agg(const short* __restrict__ XLb,
                                               const float* __restrict__ AS,
                                               const float* __restrict__ AD,
                                               const int* __restrict__ rowptr,
                                               const int* __restrict__ csr_src,
                                               const float* __restrict__ cb,
                                               const float* __restrict__ Hlin,
                                               short* __restrict__ Hb, int n_nodes) {
    int n = (blockIdx.x * blockDim.x + threadIdx.x) >> 6;
    int lane = threadIdx.x & 63;
    if (n >= n_nodes) return;
    int rs = rowptr[n], re = rowptr[n + 1];
    float4 ad4 = *(const float4*)(AD + n * 4);

    float m0 = -1e30f, m1 = -1e30f, m2 = -1e30f, m3 = -1e30f;
    for (int i = rs + lane; i < re; i += 64) {
        int s = csr_src[i];
        float4 as = *(const float4*)(AS + s * 4);
        m0 = fmaxf(m0, lrelu_(as.x + ad4.x));
        m1 = fmaxf(m1, lrelu_(as.y + ad4.y));
        m2 = fmaxf(m2, lrelu_(as.z + ad4.z));
        m3 = fmaxf(m3, lrelu_(as.w + ad4.w));
    }
#pragma unroll
    for (int off = 32; off > 0; off >>= 1) {
        m0 = fmaxf(m0, __shfl_xor(m0, off));
        m1 = fmaxf(m1, __shfl_xor(m1, off));
        m2 = fmaxf(m2, __shfl_xor(m2, off));
        m3 = fmaxf(m3, __shfl_xor(m3, off));
    }

    int h = lane >> 4;
    float mh  = (h == 0) ? m0 : (h == 1) ? m1 : (h == 2) ? m2 : m3;
    float adh = (h == 0) ? ad4.x : (h == 1) ? ad4.y : (h == 2) ? ad4.z : ad4.w;

    float4 acc = make_float4(0.f, 0.f, 0.f, 0.f);
    float den = 0.f;
    for (int i = rs; i < re; ++i) {
        int s = csr_src[i];
        float asv = AS[s * 4 + h];
        float ex = __expf(lrelu_(asv + adh) - mh);
        uint2 q = *(const uint2*)(XLb + (size_t)s * 256 + lane * 4);
        den += ex;
        acc.x += ex * bfu(q.x & 0xffff);
        acc.y += ex * bfu(q.x >> 16);
        acc.z += ex * bfu(q.y & 0xffff);
        acc.w += ex * bfu(q.y >> 16);
    }
    float inv = 1.f / (den + 1e-16f);

    size_t o = (size_t)n * 256 + lane * 4;
    float4 hv = *(const float4*)(Hlin + o);
    float4 cbv = *(const float4*)(cb + lane * 4);
    short4 ov;
    ov.x = f2bf(elu_(acc.x * inv + cbv.x + hv.x));
    ov.y = f2bf(elu_(acc.y * inv + cbv.y + hv.y));
    ov.z = f2bf(elu_(acc.z * inv + cbv.z + hv.z));
    ov.w = f2bf(elu_(acc.w * inv + cbv.w + hv.w));
    *(short4*)(Hb + o) = ov;
}

// ---------------- layer 2 projections ----------------

__global__ __launch_bounds__(256) void l2_prep(const short* __restrict__ Hin,
                                               const float* __restrict__ cW2,
                                               const float* __restrict__ lW2,
                                               const float* __restrict__ lb2,
                                               float* __restrict__ XL2,
                                               float* __restrict__ LIN2, int n_nodes) {
    int n = (blockIdx.x * blockDim.x + threadIdx.x) >> 6;
    int lane = threadIdx.x & 63;
    if (n >= n_nodes) return;
    uint2 q = *(const uint2*)(Hin + (size_t)n * 256 + lane * 4);
    float hk0 = bfu(q.x & 0xffff), hk1 = bfu(q.x >> 16);
    float hk2 = bfu(q.y & 0xffff), hk3 = bfu(q.y >> 16);
    int k = lane * 4;
    float4 w0 = *(const float4*)(cW2 + (k + 0) * 4);
    float4 w1 = *(const float4*)(cW2 + (k + 1) * 4);
    float4 w2 = *(const float4*)(cW2 + (k + 2) * 4);
    float4 w3 = *(const float4*)(cW2 + (k + 3) * 4);
    float a0 = hk0 * w0.x + hk1 * w1.x + hk2 * w2.x + hk3 * w3.x;
    float a1 = hk0 * w0.y + hk1 * w1.y + hk2 * w2.y + hk3 * w3.y;
    float a2 = hk0 * w0.z + hk1 * w1.z + hk2 * w2.z + hk3 * w3.z;
    float a3 = hk0 * w0.w + hk1 * w1.w + hk2 * w2.w + hk3 * w3.w;
    float4 lw = make_float4(lW2[k], lW2[k + 1], lW2[k + 2], lW2[k + 3]);
    float al = hk0 * lw.x + hk1 * lw.y + hk2 * lw.z + hk3 * lw.w;
#pragma unroll
    for (int off = 32; off > 0; off >>= 1) {
        a0 += __shfl_xor(a0, off); a1 += __shfl_xor(a1, off);
        a2 += __shfl_xor(a2, off); a3 += __shfl_xor(a3, off);
        al += __shfl_xor(al, off);
    }
    if (lane == 0) {
        float4 o = make_float4(a0, a1, a2, a3);
        *(float4*)(XL2 + n * 4) = o;
        LIN2[n] = al + lb2[0];
    }
}

// ---------------- layer 2 aggregation ----------------

__global__ __launch_bounds__(256) void l2_agg(const float* __restrict__ XL2,
                                              const float* __restrict__ LIN2,
                                              const float* __restrict__ cas2,
                                              const float* __restrict__ cad2,
                                              const float* __restrict__ cb2,
                                              const int* __restrict__ rowptr,
                                              const int* __restrict__ csr_src,
                                              float* __restrict__ out, int n_nodes) {
    int n = (blockIdx.x * blockDim.x + threadIdx.x) >> 6;
    int lane = threadIdx.x & 63;
    if (n >= n_nodes) return;
    int rs = rowptr[n], re = rowptr[n + 1];
    float4 xn = *(const float4*)(XL2 + n * 4);
    float cs0 = cas2[0], cs1 = cas2[1], cs2 = cas2[2], cs3 = cas2[3];
    float cd0 = cad2[0], cd1 = cad2[1], cd2 = cad2[2], cd3 = cad2[3];
    float ad0 = xn.x * cd0, ad1 = xn.y * cd1, ad2 = xn.z * cd2, ad3 = xn.w * cd3;

    float m0 = -1e30f, m1 = -1e30f, m2 = -1e30f, m3 = -1e30f;
    for (int i = rs + lane; i < re; i += 64) {
        int s = csr_src[i];
        float4 xs = *(const float4*)(XL2 + s * 4);
        m0 = fmaxf(m0, lrelu_(xs.x * cs0 + ad0));
        m1 = fmaxf(m1, lrelu_(xs.y * cs1 + ad1));
        m2 = fmaxf(m2, lrelu_(xs.z * cs2 + ad2));
        m3 = fmaxf(m3, lrelu_(xs.w * cs3 + ad3));
    }
#pragma unroll
    for (int off = 32; off > 0; off >>= 1) {
        m0 = fmaxf(m0, __shfl_xor(m0, off));
        m1 = fmaxf(m1, __shfl_xor(m1, off));
        m2 = fmaxf(m2, __shfl_xor(m2, off));
        m3 = fmaxf(m3, __shfl_xor(m3, off));
    }

    float d0 = 0.f, d1 = 0.f, d2 = 0.f, d3 = 0.f;
    float t0 = 0.f, t1 = 0.f, t2 = 0.f, t3 = 0.f;
    for (int i = rs + lane; i < re; i += 64) {
        int s = csr_src[i];
        float4 xs = *(const float4*)(XL2 + s * 4);
        float e0 = __expf(lrelu_(xs.x * cs0 + ad0) - m0);
        float e1 = __expf(lrelu_(xs.y * cs1 + ad1) - m1);
        float e2 = __expf(lrelu_(xs.z * cs2 + ad2) - m2);
        float e3 = __expf(lrelu_(xs.w * cs3 + ad3) - m3);
        d0 += e0; d1 += e1; d2 += e2; d3 += e3;
        t0 += e0 * xs.x; t1 += e1 * xs.y; t2 += e2 * xs.z; t3 += e3 * xs.w;
    }
#pragma unroll
    for (int off = 32; off > 0; off >>= 1) {
        d0 += __shfl_xor(d0, off); d1 += __shfl_xor(d1, off);
        d2 += __shfl_xor(d2, off); d3 += __shfl_xor(d3, off);
        t0 += __shfl_xor(t0, off); t1 += __shfl_xor(t1, off);
        t2 += __shfl_xor(t2, off); t3 += __shfl_xor(t3, off);
    }
    if (lane == 0) {
        float r = 0.25f * (t0 / (d0 + 1e-16f) + t1 / (d1 + 1e-16f) +
                           t2 / (d2 + 1e-16f) + t3 / (d3 + 1e-16f));
        out[n] = r + cb2[0] + LIN2[n];
    }
}

// ---------------- launch ----------------

extern "C" void kernel_launch(void* const* d_in, const int* in_sizes, int n_in,
                              void* d_out, int out_size, void* d_ws, size_t ws_size,
                              hipStream_t stream) {
    const float* x    = (const float*)d_in[0];
    const int*   ei   = (const int*)d_in[1];
    const float* cW0  = (const float*)d_in[3];
    const float* cas0 = (const float*)d_in[4];
    const float* cad0 = (const float*)d_in[5];
    const float* cb0  = (const float*)d_in[6];
    const float* lW0  = (const float*)d_in[7];
    const float* lb0  = (const float*)d_in[8];
    const float* cW1  = (const float*)d_in[9];
    const float* cas1 = (const float*)d_in[10];
    const float* cad1 = (const float*)d_in[11];
    const float* cb1  = (const float*)d_in[12];
    const float* lW1  = (const float*)d_in[13];
    const float* lb1  = (const float*)d_in[14];
    const float* cW2  = (const float*)d_in[15];
    const float* cas2 = (const float*)d_in[16];
    const float* cad2 = (const float*)d_in[17];
    const float* cb2  = (const float*)d_in[18];
    const float* lW2  = (const float*)d_in[19];
    const float* lb2  = (const float*)d_in[20];
    float* out = (float*)d_out;

    // workspace layout (~148 MB)
    short* xb   = (short*)d_ws;                 // 6.4M bf16
    short* XLb  = xb + 6400000;                 // 12.8M bf16
    short* HAb  = XLb + 12800000;
    short* HBb  = HAb + 12800000;
    short* Wt0  = HBb + 12800000;               // 512*128
    short* Wt1  = Wt0 + 65536;                  // 512*256
    float* Hlin = (float*)(Wt1 + 131072);       // 12.8M fp32
    float* AS   = Hlin + 12800000;
    float* AD   = AS + 200000;
    float* XL2  = AD + 200000;
    float* LIN2 = XL2 + 200000;
    int* deg    = (int*)(LIN2 + NN);
    int* cursor = deg + NN;
    int* rowptr = cursor + NN;                  // NN+1
    int* excl   = rowptr + NN + 4;
    int* bsum   = excl + NN;                    // 64
    int* csr_src= bsum + 64;                    // ET_

    dim3 b256(256);
    dim3 gEdges((ET_ + 255) / 256);
    dim3 gNodesWave((NN + 3) / 4);
    dim3 gemmGrid((NN + 127) / 128, 4);

    // CSR build
    zero_k<<<dim3((2 * NN + 255) / 256), b256, 0, stream>>>(deg, 2 * NN);
    degree_k<<<gEdges, b256, 0, stream>>>(ei, deg);
    scan1<<<dim3((NN + 1023) / 1024), dim3(1024), 0, stream>>>(deg, excl, bsum, NN);
    scan2<<<dim3(1), dim3(64), 0, stream>>>(bsum, (NN + 1023) / 1024);
    scan3<<<dim3((NN + 255) / 256), b256, 0, stream>>>(excl, bsum, rowptr, NN);
    scatter_k<<<gEdges, b256, 0, stream>>>(ei, rowptr, cursor, csr_src);

    // dtype prep
    f2bf_k<<<dim3(6400000 / 4 / 256), b256, 0, stream>>>(x, xb, 6400000);
    prep_w<<<dim3(512 * 128 / 256), b256, 0, stream>>>(cW0, lW0, Wt0, 128);
    prep_w<<<dim3(512 * 256 / 256), b256, 0, stream>>>(cW1, lW1, Wt1, 256);

    // layer 0
    gemm_bf16<<<gemmGrid, b256, 0, stream>>>(xb, Wt0, lb0, XLb, Hlin, NN, 128);
    attn_prep<<<gNodesWave, b256, 0, stream>>>(XLb, cas0, cad0, AS, AD, NN);
    gat_agg<<<gNodesWave, b256, 0, stream>>>(XLb, AS, AD, rowptr, csr_src, cb0, Hlin, HAb, NN);

    // layer 1
    gemm_bf16<<<gemmGrid, b256, 0, stream>>>(HAb, Wt1, lb1, XLb, Hlin, NN, 256);
    attn_prep<<<gNodesWave, b256, 0, stream>>>(XLb, cas1, cad1, AS, AD, NN);
    gat_agg<<<gNodesWave, b256, 0, stream>>>(XLb, AS, AD, rowptr, csr_src, cb1, Hlin, HBb, NN);

    // layer 2
    l2_prep<<<gNodesWave, b256, 0, stream>>>(HBb, cW2, lW2, lb2, XL2, LIN2, NN);
    l2_agg<<<gNodesWave, b256, 0, stream>>>(XL2, LIN2, cas2, cad2, cb2, rowptr, csr_src, out, NN);
}

// Round 3
// 576.398 us; speedup vs baseline: 1.6285x; 1.0281x over previous
//
#include <hip/hip_runtime.h>
#include <cstddef>
#include <cstdint>

#define NN 50000
#define EE 800000
#define ET_ (EE + NN)

typedef __attribute__((ext_vector_type(8))) short bf16x8;
typedef __attribute__((ext_vector_type(4))) float f32x4;

__device__ __forceinline__ float lrelu_(float x) { return x > 0.f ? x : 0.2f * x; }
__device__ __forceinline__ float elu_(float x)   { return x > 0.f ? x : (__expf(x) - 1.f); }
__device__ __forceinline__ short f2bf(float f) {
    unsigned u = __float_as_uint(f);
    unsigned r = (u + 0x7fffu + ((u >> 16) & 1u)) >> 16;
    return (short)r;
}
__device__ __forceinline__ float bfu(unsigned u16v) { return __uint_as_float(u16v << 16); }

#define GL16(gp, lp) __builtin_amdgcn_global_load_lds( \
    (const __attribute__((address_space(1))) unsigned int*)(gp), \
    (__attribute__((address_space(3))) unsigned int*)(lp), 16, 0, 0)

// ---------------- CSR build ----------------

__global__ __launch_bounds__(256) void degree_k(const int* __restrict__ ei, int* __restrict__ deg) {
    int e = blockIdx.x * blockDim.x + threadIdx.x;
    if (e >= ET_) return;
    int d = (e < EE) ? ei[EE + e] : (e - EE);
    atomicAdd(&deg[d], 1);
}

__global__ __launch_bounds__(1024) void scan1(const int* __restrict__ deg, int* __restrict__ excl,
                                              int* __restrict__ bsum, int n) {
    __shared__ int s[1024];
    int tid = threadIdx.x;
    int gid = blockIdx.x * 1024 + tid;
    int v = (gid < n) ? deg[gid] : 0;
    s[tid] = v;
    __syncthreads();
    for (int off = 1; off < 1024; off <<= 1) {
        int t = (tid >= off) ? s[tid - off] : 0;
        __syncthreads();
        s[tid] += t;
        __syncthreads();
    }
    if (gid < n) excl[gid] = s[tid] - v;
    if (tid == 1023) bsum[blockIdx.x] = s[1023];
}

__global__ __launch_bounds__(64) void scan2(int* bsum, int nb) {
    int tid = threadIdx.x;
    int v = (tid < nb) ? bsum[tid] : 0;
    int s = v;
#pragma unroll
    for (int off = 1; off < 64; off <<= 1) {
        int t = __shfl_up(s, off);
        if (tid >= off) s += t;
    }
    if (tid < nb) bsum[tid] = s - v;   // exclusive
}

__global__ __launch_bounds__(256) void scan3(const int* __restrict__ excl, const int* __restrict__ bsum,
                                             int* __restrict__ rowptr, int n) {
    int i = blockIdx.x * blockDim.x + threadIdx.x;
    if (i < n) rowptr[i] = excl[i] + bsum[i >> 10];
    if (i == 0) rowptr[n] = ET_;
}

__global__ __launch_bounds__(256) void scatter_k(const int* __restrict__ ei,
                                                 const int* __restrict__ rowptr,
                                                 int* __restrict__ cursor,
                                                 int* __restrict__ csr_src) {
    int e = blockIdx.x * blockDim.x + threadIdx.x;
    if (e >= ET_) return;
    int s, d;
    if (e < EE) { s = ei[e]; d = ei[EE + e]; } else { s = e - EE; d = e - EE; }
    int pos = atomicAdd(&cursor[d], 1);
    csr_src[rowptr[d] + pos] = s;
}

// ---------------- fused dtype prep: x -> bf16, pack Wt0/Wt1 ----------------

__global__ __launch_bounds__(256) void prep_all(const float* __restrict__ x,
                                                const float* __restrict__ cW0, const float* __restrict__ lW0,
                                                const float* __restrict__ cW1, const float* __restrict__ lW1,
                                                short* __restrict__ xb, short* __restrict__ Wt0,
                                                short* __restrict__ Wt1) {
    int i = blockIdx.x * 256 + threadIdx.x;
    if (i < 1600000) {                       // x: 6.4M floats, 4 per thread
        float4 v = *(const float4*)(x + (size_t)i * 4);
        short4 o;
        o.x = f2bf(v.x); o.y = f2bf(v.y); o.z = f2bf(v.z); o.w = f2bf(v.w);
        *(short4*)(xb + (size_t)i * 4) = o;
        return;
    }
    i -= 1600000;
    if (i < 512 * 128) {                     // Wt0[n][k] from cW0/lW0 (K=128)
        int n = i >> 7, k = i & 127;
        float v = (n < 256) ? cW0[k * 256 + n] : lW0[k * 256 + (n - 256)];
        Wt0[i] = f2bf(v);
        return;
    }
    i -= 512 * 128;
    if (i < 512 * 256) {                     // Wt1[n][k] (K=256)
        int n = i >> 8, k = i & 255;
        float v = (n < 256) ? cW1[k * 256 + n] : lW1[k * 256 + (n - 256)];
        Wt1[i] = f2bf(v);
    }
}

// ---------------- bf16 MFMA GEMM: out[M,512] = A[M,K] @ Wt^T ----------------
// cols 0..255 -> XLb (bf16); cols 256..511 -> Hlinb (bf16, +biasLin)

__global__ __launch_bounds__(256) void gemm_bf16(const short* __restrict__ A,
                                                 const short* __restrict__ Wt,
                                                 const float* __restrict__ biasLin,
                                                 short* __restrict__ XLb,
                                                 short* __restrict__ Hlinb,
                                                 int M, int K) {
    __shared__ short As[128 * 32];
    __shared__ short Bs[128 * 32];
    const int tid = threadIdx.x;
    const int lane = tid & 63;
    const int wid = tid >> 6;
    const int bm = blockIdx.x * 128;
    const int col0 = blockIdx.y * 128;
    const int wr = wid >> 1, wc = wid & 1;

    f32x4 acc[4][4];
#pragma unroll
    for (int i = 0; i < 4; ++i)
#pragma unroll
        for (int j = 0; j < 4; ++j) acc[i][j] = (f32x4){0.f, 0.f, 0.f, 0.f};

    const int lrow = lane & 15, lk = lane >> 4;

    for (int k0 = 0; k0 < K; k0 += 32) {
#pragma unroll
        for (int it = 0; it < 2; ++it) {
            const int flat = tid + it * 256;
            const int row = flat >> 2, slot = flat & 3;
            const int ss = slot ^ (row & 3);      // pre-swizzled source chunk
            int ar = bm + row; ar = (ar < M) ? ar : (M - 1);
            GL16(A + (size_t)ar * K + k0 + ss * 8, As + flat * 8);
            GL16(Wt + (size_t)(col0 + row) * K + k0 + ss * 8, Bs + flat * 8);
        }
        __syncthreads();
        bf16x8 af[4], bfr[4];
#pragma unroll
        for (int mi = 0; mi < 4; ++mi) {
            const int r = wr * 64 + mi * 16 + lrow;
            af[mi] = *(const bf16x8*)(As + (r * 4 + (lk ^ (r & 3))) * 8);
        }
#pragma unroll
        for (int ni = 0; ni < 4; ++ni) {
            const int c = wc * 64 + ni * 16 + lrow;
            bfr[ni] = *(const bf16x8*)(Bs + (c * 4 + (lk ^ (c & 3))) * 8);
        }
#pragma unroll
        for (int mi = 0; mi < 4; ++mi)
#pragma unroll
            for (int ni = 0; ni < 4; ++ni)
                acc[mi][ni] = __builtin_amdgcn_mfma_f32_16x16x32_bf16(af[mi], bfr[ni], acc[mi][ni], 0, 0, 0);
        __syncthreads();
    }

    const int lrow4 = (lane >> 4) * 4;
    const bool isLin = (col0 >= 256);
#pragma unroll
    for (int mi = 0; mi < 4; ++mi) {
#pragma unroll
        for (int ni = 0; ni < 4; ++ni) {
            const int col = col0 + wc * 64 + ni * 16 + (lane & 15);
#pragma unroll
            for (int rr = 0; rr < 4; ++rr) {
                const int grow = bm + wr * 64 + mi * 16 + lrow4 + rr;
                if (grow < M) {
                    float v = acc[mi][ni][rr];
                    if (isLin) {
                        const int c = col - 256;
                        Hlinb[(size_t)grow * 256 + c] = f2bf(v + biasLin[c]);
                    } else {
                        XLb[(size_t)grow * 256 + col] = f2bf(v);
                    }
                }
            }
        }
    }
}

// ---------------- attention prep: a_s/a_d per node per head ----------------

__global__ __launch_bounds__(256) void attn_prep(const short* __restrict__ XLb,
                                                 const float* __restrict__ cas,
                                                 const float* __restrict__ cad,
                                                 float* __restrict__ AS,
                                                 float* __restrict__ AD, int n_nodes) {
    int n = (blockIdx.x * blockDim.x + threadIdx.x) >> 6;
    int lane = threadIdx.x & 63;
    if (n >= n_nodes) return;
    uint2 q = *(const uint2*)(XLb + (size_t)n * 256 + lane * 4);
    float x0 = bfu(q.x & 0xffff), x1 = bfu(q.x >> 16);
    float x2 = bfu(q.y & 0xffff), x3 = bfu(q.y >> 16);
    float4 sv = *(const float4*)(cas + lane * 4);
    float4 dv = *(const float4*)(cad + lane * 4);
    float ps = x0 * sv.x + x1 * sv.y + x2 * sv.z + x3 * sv.w;
    float pd = x0 * dv.x + x1 * dv.y + x2 * dv.z + x3 * dv.w;
#pragma unroll
    for (int off = 1; off < 16; off <<= 1) {
        ps += __shfl_xor(ps, off);
        pd += __shfl_xor(pd, off);
    }
    if ((lane & 15) == 0) {
        AS[n * 4 + (lane >> 4)] = ps;
        AD[n * 4 + (lane >> 4)] = pd;
    }
}

// ---------------- GAT aggregation: block per node, 4-wave edge split ----------------

__global__ __launch_bounds__(256) void gat_agg(const short* __restrict__ XLb,
                                               const float* __restrict__ AS,
                                               const float* __restrict__ AD,
                                               const int* __restrict__ rowptr,
                                               const int* __restrict__ csr_src,
                                               const float* __restrict__ cb,
                                               const short* __restrict__ Hlinb,
                                               short* __restrict__ Hb) {
    __shared__ int   sIdx[256];
    __shared__ float sSc[4][256];
    __shared__ float sAcc[4][256];
    __shared__ float sRed[4][4];
    __shared__ float sDen[4][4];

    const int n = blockIdx.x;
    const int tid = threadIdx.x;
    const int lane = tid & 63;
    const int w = tid >> 6;
    const int rs = rowptr[n], re = rowptr[n + 1];
    const int deg = re - rs;
    const float4 ad4 = *(const float4*)(AD + n * 4);
    const int h = lane >> 4;
    const bool single = (deg <= 256);

    // pass A: stage src idx + per-head scores (single-chunk case), running block max
    float m0 = -1e30f, m1 = -1e30f, m2 = -1e30f, m3 = -1e30f;
    for (int base = 0; base < deg; base += 256) {
        int idx = base + tid;
        if (idx < deg) {
            int s = csr_src[rs + idx];
            float4 a = *(const float4*)(AS + s * 4);
            float c0 = lrelu_(a.x + ad4.x);
            float c1 = lrelu_(a.y + ad4.y);
            float c2 = lrelu_(a.z + ad4.z);
            float c3 = lrelu_(a.w + ad4.w);
            if (single) {
                sIdx[tid] = s;
                sSc[0][tid] = c0; sSc[1][tid] = c1; sSc[2][tid] = c2; sSc[3][tid] = c3;
            }
            m0 = fmaxf(m0, c0); m1 = fmaxf(m1, c1); m2 = fmaxf(m2, c2); m3 = fmaxf(m3, c3);
        }
    }
#pragma unroll
    for (int off = 32; off > 0; off >>= 1) {
        m0 = fmaxf(m0, __shfl_xor(m0, off));
        m1 = fmaxf(m1, __shfl_xor(m1, off));
        m2 = fmaxf(m2, __shfl_xor(m2, off));
        m3 = fmaxf(m3, __shfl_xor(m3, off));
    }
    if (lane == 0) { sRed[w][0] = m0; sRed[w][1] = m1; sRed[w][2] = m2; sRed[w][3] = m3; }
    __syncthreads();
    const float mh = fmaxf(fmaxf(sRed[0][h], sRed[1][h]), fmaxf(sRed[2][h], sRed[3][h]));

    // pass C: 4 waves split the edge list; per-lane 4 channels
    float4 acc = make_float4(0.f, 0.f, 0.f, 0.f);
    float den = 0.f;
    for (int base = 0; base < deg; base += 256) {
        int cnt = min(256, deg - base);
        if (!single) {                 // restage this chunk (rare path)
            __syncthreads();
            int idx = base + tid;
            if (tid < cnt) {
                int s = csr_src[rs + idx];
                float4 a = *(const float4*)(AS + s * 4);
                sIdx[tid] = s;
                sSc[0][tid] = lrelu_(a.x + ad4.x);
                sSc[1][tid] = lrelu_(a.y + ad4.y);
                sSc[2][tid] = lrelu_(a.z + ad4.z);
                sSc[3][tid] = lrelu_(a.w + ad4.w);
            }
            __syncthreads();
        }
        for (int j = w; j < cnt; j += 4) {
            int s = sIdx[j];
            float ex = __expf(sSc[h][j] - mh);
            uint2 q = *(const uint2*)(XLb + (size_t)s * 256 + lane * 4);
            den += ex;
            acc.x += ex * bfu(q.x & 0xffff);
            acc.y += ex * bfu(q.x >> 16);
            acc.z += ex * bfu(q.y & 0xffff);
            acc.w += ex * bfu(q.y >> 16);
        }
    }

    // combine partials across waves
    *(float4*)(&sAcc[w][lane * 4]) = acc;
    if ((lane & 15) == 0) sDen[w][h] = den;
    __syncthreads();
    if (w == 0) {
        float4 a0 = *(const float4*)(&sAcc[0][lane * 4]);
        float4 a1 = *(const float4*)(&sAcc[1][lane * 4]);
        float4 a2 = *(const float4*)(&sAcc[2][lane * 4]);
        float4 a3 = *(const float4*)(&sAcc[3][lane * 4]);
        float dsum = sDen[0][h] + sDen[1][h] + sDen[2][h] + sDen[3][h];
        float inv = 1.f / (dsum + 1e-16f);
        size_t o = (size_t)n * 256 + lane * 4;
        uint2 hq = *(const uint2*)(Hlinb + o);
        float4 cbv = *(const float4*)(cb + lane * 4);
        short4 ov;
        ov.x = f2bf(elu_((a0.x + a1.x + a2.x + a3.x) * inv + cbv.x + bfu(hq.x & 0xffff)));
        ov.y = f2bf(elu_((a0.y + a1.y + a2.y + a3.y) * inv + cbv.y + bfu(hq.x >> 16)));
        ov.z = f2bf(elu_((a0.z + a1.z + a2.z + a3.z) * inv + cbv.z + bfu(hq.y & 0xffff)));
        ov.w = f2bf(elu_((a0.w + a1.w + a2.w + a3.w) * inv + cbv.w + bfu(hq.y >> 16)));
        *(short4*)(Hb + o) = ov;
    }
}

// ---------------- layer 2 projections ----------------

__global__ __launch_bounds__(256) void l2_prep(const short* __restrict__ Hin,
                                               const float* __restrict__ cW2,
                                               const float* __restrict__ lW2,
                                               const float* __restrict__ lb2,
                                               float* __restrict__ XL2,
                                               float* __restrict__ LIN2, int n_nodes) {
    int n = (blockIdx.x * blockDim.x + threadIdx.x) >> 6;
    int lane = threadIdx.x & 63;
    if (n >= n_nodes) return;
    uint2 q = *(const uint2*)(Hin + (size_t)n * 256 + lane * 4);
    float hk0 = bfu(q.x & 0xffff), hk1 = bfu(q.x >> 16);
    float hk2 = bfu(q.y & 0xffff), hk3 = bfu(q.y >> 16);
    int k = lane * 4;
    float4 w0 = *(const float4*)(cW2 + (k + 0) * 4);
    float4 w1 = *(const float4*)(cW2 + (k + 1) * 4);
    float4 w2 = *(const float4*)(cW2 + (k + 2) * 4);
    float4 w3 = *(const float4*)(cW2 + (k + 3) * 4);
    float a0 = hk0 * w0.x + hk1 * w1.x + hk2 * w2.x + hk3 * w3.x;
    float a1 = hk0 * w0.y + hk1 * w1.y + hk2 * w2.y + hk3 * w3.y;
    float a2 = hk0 * w0.z + hk1 * w1.z + hk2 * w2.z + hk3 * w3.z;
    float a3 = hk0 * w0.w + hk1 * w1.w + hk2 * w2.w + hk3 * w3.w;
    float4 lw = make_float4(lW2[k], lW2[k + 1], lW2[k + 2], lW2[k + 3]);
    float al = hk0 * lw.x + hk1 * lw.y + hk2 * lw.z + hk3 * lw.w;
#pragma unroll
    for (int off = 32; off > 0; off >>= 1) {
        a0 += __shfl_xor(a0, off); a1 += __shfl_xor(a1, off);
        a2 += __shfl_xor(a2, off); a3 += __shfl_xor(a3, off);
        al += __shfl_xor(al, off);
    }
    if (lane == 0) {
        float4 o = make_float4(a0, a1, a2, a3);
        *(float4*)(XL2 + n * 4) = o;
        LIN2[n] = al + lb2[0];
    }
}

// ---------------- layer 2 aggregation ----------------

__global__ __launch_bounds__(256) void l2_agg(const float* __restrict__ XL2,
                                              const float* __restrict__ LIN2,
                                              const float* __restrict__ cas2,
                                              const float* __restrict__ cad2,
                                              const float* __restrict__ cb2,
                                              const int* __restrict__ rowptr,
                                              const int* __restrict__ csr_src,
                                              float* __restrict__ out, int n_nodes) {
    int n = (blockIdx.x * blockDim.x + threadIdx.x) >> 6;
    int lane = threadIdx.x & 63;
    if (n >= n_nodes) return;
    int rs = rowptr[n], re = rowptr[n + 1];
    float4 xn = *(const float4*)(XL2 + n * 4);
    float cs0 = cas2[0], cs1 = cas2[1], cs2 = cas2[2], cs3 = cas2[3];
    float cd0 = cad2[0], cd1 = cad2[1], cd2 = cad2[2], cd3 = cad2[3];
    float ad0 = xn.x * cd0, ad1 = xn.y * cd1, ad2 = xn.z * cd2, ad3 = xn.w * cd3;

    float m0 = -1e30f, m1 = -1e30f, m2 = -1e30f, m3 = -1e30f;
    for (int i = rs + lane; i < re; i += 64) {
        int s = csr_src[i];
        float4 xs = *(const float4*)(XL2 + s * 4);
        m0 = fmaxf(m0, lrelu_(xs.x * cs0 + ad0));
        m1 = fmaxf(m1, lrelu_(xs.y * cs1 + ad1));
        m2 = fmaxf(m2, lrelu_(xs.z * cs2 + ad2));
        m3 = fmaxf(m3, lrelu_(xs.w * cs3 + ad3));
    }
#pragma unroll
    for (int off = 32; off > 0; off >>= 1) {
        m0 = fmaxf(m0, __shfl_xor(m0, off));
        m1 = fmaxf(m1, __shfl_xor(m1, off));
        m2 = fmaxf(m2, __shfl_xor(m2, off));
        m3 = fmaxf(m3, __shfl_xor(m3, off));
    }

    float d0 = 0.f, d1 = 0.f, d2 = 0.f, d3 = 0.f;
    float t0 = 0.f, t1 = 0.f, t2 = 0.f, t3 = 0.f;
    for (int i = rs + lane; i < re; i += 64) {
        int s = csr_src[i];
        float4 xs = *(const float4*)(XL2 + s * 4);
        float e0 = __expf(lrelu_(xs.x * cs0 + ad0) - m0);
        float e1 = __expf(lrelu_(xs.y * cs1 + ad1) - m1);
        float e2 = __expf(lrelu_(xs.z * cs2 + ad2) - m2);
        float e3 = __expf(lrelu_(xs.w * cs3 + ad3) - m3);
        d0 += e0; d1 += e1; d2 += e2; d3 += e3;
        t0 += e0 * xs.x; t1 += e1 * xs.y; t2 += e2 * xs.z; t3 += e3 * xs.w;
    }
#pragma unroll
    for (int off = 32; off > 0; off >>= 1) {
        d0 += __shfl_xor(d0, off); d1 += __shfl_xor(d1, off);
        d2 += __shfl_xor(d2, off); d3 += __shfl_xor(d3, off);
        t0 += __shfl_xor(t0, off); t1 += __shfl_xor(t1, off);
        t2 += __shfl_xor(t2, off); t3 += __shfl_xor(t3, off);
    }
    if (lane == 0) {
        float r = 0.25f * (t0 / (d0 + 1e-16f) + t1 / (d1 + 1e-16f) +
                           t2 / (d2 + 1e-16f) + t3 / (d3 + 1e-16f));
        out[n] = r + cb2[0] + LIN2[n];
    }
}

// ---------------- launch ----------------

extern "C" void kernel_launch(void* const* d_in, const int* in_sizes, int n_in,
                              void* d_out, int out_size, void* d_ws, size_t ws_size,
                              hipStream_t stream) {
    const float* x    = (const float*)d_in[0];
    const int*   ei   = (const int*)d_in[1];
    const float* cW0  = (const float*)d_in[3];
    const float* cas0 = (const float*)d_in[4];
    const float* cad0 = (const float*)d_in[5];
    const float* cb0  = (const float*)d_in[6];
    const float* lW0  = (const float*)d_in[7];
    const float* lb0  = (const float*)d_in[8];
    const float* cW1  = (const float*)d_in[9];
    const float* cas1 = (const float*)d_in[10];
    const float* cad1 = (const float*)d_in[11];
    const float* cb1  = (const float*)d_in[12];
    const float* lW1  = (const float*)d_in[13];
    const float* lb1  = (const float*)d_in[14];
    const float* cW2  = (const float*)d_in[15];
    const float* cas2 = (const float*)d_in[16];
    const float* cad2 = (const float*)d_in[17];
    const float* cb2  = (const float*)d_in[18];
    const float* lW2  = (const float*)d_in[19];
    const float* lb2  = (const float*)d_in[20];
    float* out = (float*)d_out;

    // workspace layout (~122 MB)
    short* xb    = (short*)d_ws;                 // 6.4M bf16
    short* XLb   = xb + 6400000;                 // 12.8M bf16
    short* HAb   = XLb + 12800000;
    short* HBb   = HAb + 12800000;
    short* Hlinb = HBb + 12800000;               // 12.8M bf16
    short* Wt0   = Hlinb + 12800000;             // 512*128
    short* Wt1   = Wt0 + 65536;                  // 512*256
    float* AS    = (float*)(Wt1 + 131072);
    float* AD    = AS + 200000;
    float* XL2   = AD + 200000;
    float* LIN2  = XL2 + 200000;
    int* deg     = (int*)(LIN2 + NN);
    int* cursor  = deg + NN;
    int* rowptr  = cursor + NN;                  // NN+1
    int* excl    = rowptr + NN + 4;
    int* bsum    = excl + NN;                    // 64
    int* csr_src = bsum + 64;                    // ET_

    dim3 b256(256);
    dim3 gEdges((ET_ + 255) / 256);
    dim3 gNodesWave((NN + 3) / 4);
    dim3 gemmGrid((NN + 127) / 128, 4);

    // CSR build (deg+cursor zeroed in one memset; they are contiguous)
    hipMemsetAsync(deg, 0, 2 * (size_t)NN * sizeof(int), stream);
    prep_all<<<dim3(7018), b256, 0, stream>>>(x, cW0, lW0, cW1, lW1, xb, Wt0, Wt1);
    degree_k<<<gEdges, b256, 0, stream>>>(ei, deg);
    scan1<<<dim3((NN + 1023) / 1024), dim3(1024), 0, stream>>>(deg, excl, bsum, NN);
    scan2<<<dim3(1), dim3(64), 0, stream>>>(bsum, (NN + 1023) / 1024);
    scan3<<<dim3((NN + 255) / 256), b256, 0, stream>>>(excl, bsum, rowptr, NN);
    scatter_k<<<gEdges, b256, 0, stream>>>(ei, rowptr, cursor, csr_src);

    // layer 0
    gemm_bf16<<<gemmGrid, b256, 0, stream>>>(xb, Wt0, lb0, XLb, Hlinb, NN, 128);
    attn_prep<<<gNodesWave, b256, 0, stream>>>(XLb, cas0, cad0, AS, AD, NN);
    gat_agg<<<dim3(NN), b256, 0, stream>>>(XLb, AS, AD, rowptr, csr_src, cb0, Hlinb, HAb);

    // layer 1
    gemm_bf16<<<gemmGrid, b256, 0, stream>>>(HAb, Wt1, lb1, XLb, Hlinb, NN, 256);
    attn_prep<<<gNodesWave, b256, 0, stream>>>(XLb, cas1, cad1, AS, AD, NN);
    gat_agg<<<dim3(NN), b256, 0, stream>>>(XLb, AS, AD, rowptr, csr_src, cb1, Hlinb, HBb);

    // layer 2
    l2_prep<<<gNodesWave, b256, 0, stream>>>(HBb, cW2, lW2, lb2, XL2, LIN2, NN);
    l2_agg<<<gNodesWave, b256, 0, stream>>>(XL2, LIN2, cas2, cad2, cb2, rowptr, csr_src, out, NN);
}

// Round 5
// 511.398 us; speedup vs baseline: 1.8355x; 1.1271x over previous
//
#include <hip/hip_runtime.h>
#include <cstddef>
#include <cstdint>

#define NN 50000
#define EE 800000
#define ET_ (EE + NN)

typedef __attribute__((ext_vector_type(8))) short bf16x8;
typedef __attribute__((ext_vector_type(4))) float f32x4;

__device__ __forceinline__ float lrelu_(float x) { return x > 0.f ? x : 0.2f * x; }
__device__ __forceinline__ float elu_(float x)   { return x > 0.f ? x : (__expf(x) - 1.f); }
__device__ __forceinline__ short f2bf(float f) {
    unsigned u = __float_as_uint(f);
    unsigned r = (u + 0x7fffu + ((u >> 16) & 1u)) >> 16;
    return (short)r;
}
__device__ __forceinline__ float bflo(unsigned u) { return __uint_as_float(u << 16); }
__device__ __forceinline__ float bfhi(unsigned u) { return __uint_as_float(u & 0xffff0000u); }

#define GL16(gp, lp) __builtin_amdgcn_global_load_lds( \
    (const __attribute__((address_space(1))) unsigned int*)(gp), \
    (__attribute__((address_space(3))) unsigned int*)(lp), 16, 0, 0)

// ---------------- CSR build ----------------

__global__ __launch_bounds__(256) void degree_k(const int* __restrict__ ei, int* __restrict__ deg) {
    int e = blockIdx.x * blockDim.x + threadIdx.x;
    if (e >= ET_) return;
    int d = (e < EE) ? ei[EE + e] : (e - EE);
    atomicAdd(&deg[d], 1);
}

// block-scan + atomic allocator: rowptr[i] = base(block) + excl_in_block
__global__ __launch_bounds__(1024) void alloc_scan(const int* __restrict__ deg, int* __restrict__ rowptr,
                                                   int* __restrict__ gcnt, int n) {
    __shared__ int s[1024];
    __shared__ int basesh;
    int tid = threadIdx.x;
    int gid = blockIdx.x * 1024 + tid;
    int v = (gid < n) ? deg[gid] : 0;
    s[tid] = v;
    __syncthreads();
    for (int off = 1; off < 1024; off <<= 1) {
        int t = (tid >= off) ? s[tid - off] : 0;
        __syncthreads();
        s[tid] += t;
        __syncthreads();
    }
    if (tid == 1023) basesh = atomicAdd(gcnt, s[1023]);
    __syncthreads();
    if (gid < n) rowptr[gid] = basesh + s[tid] - v;
}

__global__ __launch_bounds__(256) void scatter_k(const int* __restrict__ ei,
                                                 const int* __restrict__ rowptr,
                                                 int* __restrict__ cursor,
                                                 int* __restrict__ csr_src) {
    int e = blockIdx.x * blockDim.x + threadIdx.x;
    if (e >= ET_) return;
    int s, d;
    if (e < EE) { s = ei[e]; d = ei[EE + e]; } else { s = e - EE; d = e - EE; }
    int pos = atomicAdd(&cursor[d], 1);
    csr_src[rowptr[d] + pos] = s;
}

// ---------------- fused dtype prep: x -> bf16, pack Wt0/Wt1 ----------------

__global__ __launch_bounds__(256) void prep_all(const float* __restrict__ x,
                                                const float* __restrict__ cW0, const float* __restrict__ lW0,
                                                const float* __restrict__ cW1, const float* __restrict__ lW1,
                                                short* __restrict__ xb, short* __restrict__ Wt0,
                                                short* __restrict__ Wt1) {
    int i = blockIdx.x * 256 + threadIdx.x;
    if (i < 1600000) {                       // x: 6.4M floats, 4 per thread
        float4 v = *(const float4*)(x + (size_t)i * 4);
        short4 o;
        o.x = f2bf(v.x); o.y = f2bf(v.y); o.z = f2bf(v.z); o.w = f2bf(v.w);
        *(short4*)(xb + (size_t)i * 4) = o;
        return;
    }
    i -= 1600000;
    if (i < 512 * 128) {                     // Wt0[n][k] from cW0/lW0 (K=128)
        int n = i >> 7, k = i & 127;
        float v = (n < 256) ? cW0[k * 256 + n] : lW0[k * 256 + (n - 256)];
        Wt0[i] = f2bf(v);
        return;
    }
    i -= 512 * 128;
    if (i < 512 * 256) {                     // Wt1[n][k] (K=256)
        int n = i >> 8, k = i & 255;
        float v = (n < 256) ? cW1[k * 256 + n] : lW1[k * 256 + (n - 256)];
        Wt1[i] = f2bf(v);
    }
}

// ---------------- bf16 MFMA GEMM: out[M,512] = A[M,K] @ Wt^T ----------------

__global__ __launch_bounds__(256) void gemm_bf16(const short* __restrict__ A,
                                                 const short* __restrict__ Wt,
                                                 const float* __restrict__ biasLin,
                                                 short* __restrict__ XLb,
                                                 short* __restrict__ Hlinb,
                                                 int M, int K) {
    __shared__ short As[128 * 32];
    __shared__ short Bs[128 * 32];
    const int tid = threadIdx.x;
    const int lane = tid & 63;
    const int wid = tid >> 6;
    const int bm = blockIdx.x * 128;
    const int col0 = blockIdx.y * 128;
    const int wr = wid >> 1, wc = wid & 1;

    f32x4 acc[4][4];
#pragma unroll
    for (int i = 0; i < 4; ++i)
#pragma unroll
        for (int j = 0; j < 4; ++j) acc[i][j] = (f32x4){0.f, 0.f, 0.f, 0.f};

    const int lrow = lane & 15, lk = lane >> 4;

    for (int k0 = 0; k0 < K; k0 += 32) {
#pragma unroll
        for (int it = 0; it < 2; ++it) {
            const int flat = tid + it * 256;
            const int row = flat >> 2, slot = flat & 3;
            const int ss = slot ^ (row & 3);      // pre-swizzled source chunk
            int ar = bm + row; ar = (ar < M) ? ar : (M - 1);
            GL16(A + (size_t)ar * K + k0 + ss * 8, As + flat * 8);
            GL16(Wt + (size_t)(col0 + row) * K + k0 + ss * 8, Bs + flat * 8);
        }
        __syncthreads();
        bf16x8 af[4], bfr[4];
#pragma unroll
        for (int mi = 0; mi < 4; ++mi) {
            const int r = wr * 64 + mi * 16 + lrow;
            af[mi] = *(const bf16x8*)(As + (r * 4 + (lk ^ (r & 3))) * 8);
        }
#pragma unroll
        for (int ni = 0; ni < 4; ++ni) {
            const int c = wc * 64 + ni * 16 + lrow;
            bfr[ni] = *(const bf16x8*)(Bs + (c * 4 + (lk ^ (c & 3))) * 8);
        }
#pragma unroll
        for (int mi = 0; mi < 4; ++mi)
#pragma unroll
            for (int ni = 0; ni < 4; ++ni)
                acc[mi][ni] = __builtin_amdgcn_mfma_f32_16x16x32_bf16(af[mi], bfr[ni], acc[mi][ni], 0, 0, 0);
        __syncthreads();
    }

    const int lrow4 = (lane >> 4) * 4;
    const bool isLin = (col0 >= 256);
#pragma unroll
    for (int mi = 0; mi < 4; ++mi) {
#pragma unroll
        for (int ni = 0; ni < 4; ++ni) {
            const int col = col0 + wc * 64 + ni * 16 + (lane & 15);
#pragma unroll
            for (int rr = 0; rr < 4; ++rr) {
                const int grow = bm + wr * 64 + mi * 16 + lrow4 + rr;
                if (grow < M) {
                    float v = acc[mi][ni][rr];
                    if (isLin) {
                        const int c = col - 256;
                        Hlinb[(size_t)grow * 256 + c] = f2bf(v + biasLin[c]);
                    } else {
                        XLb[(size_t)grow * 256 + col] = f2bf(v);
                    }
                }
            }
        }
    }
}

// ---------------- attention prep: a_s/a_d per node per head ----------------

__global__ __launch_bounds__(256) void attn_prep(const short* __restrict__ XLb,
                                                 const float* __restrict__ cas,
                                                 const float* __restrict__ cad,
                                                 float* __restrict__ AS,
                                                 float* __restrict__ AD, int n_nodes) {
    int n = (blockIdx.x * blockDim.x + threadIdx.x) >> 6;
    int lane = threadIdx.x & 63;
    if (n >= n_nodes) return;
    uint2 q = *(const uint2*)(XLb + (size_t)n * 256 + lane * 4);
    float x0 = bflo(q.x), x1 = bfhi(q.x);
    float x2 = bflo(q.y), x3 = bfhi(q.y);
    float4 sv = *(const float4*)(cas + lane * 4);
    float4 dv = *(const float4*)(cad + lane * 4);
    float ps = x0 * sv.x + x1 * sv.y + x2 * sv.z + x3 * sv.w;
    float pd = x0 * dv.x + x1 * dv.y + x2 * dv.z + x3 * dv.w;
#pragma unroll
    for (int off = 1; off < 16; off <<= 1) {
        ps += __shfl_xor(ps, off);
        pd += __shfl_xor(pd, off);
    }
    if ((lane & 15) == 0) {
        AS[n * 4 + (lane >> 4)] = ps;
        AD[n * 4 + (lane >> 4)] = pd;
    }
}

// ---------------- GAT aggregation: wave per node, lane per edge ----------------
// scores lane-parallel; payload gathered 2 rows / wave-instruction (1 KB).

__global__ __launch_bounds__(256) void gat_agg(const short* __restrict__ XLb,
                                               const float* __restrict__ AS,
                                               const float* __restrict__ AD,
                                               const int* __restrict__ rowptr,
                                               const int* __restrict__ degarr,
                                               const int* __restrict__ csr_src,
                                               const float* __restrict__ cb,
                                               const short* __restrict__ Hlinb,
                                               short* __restrict__ Hb, int n_nodes) {
    __shared__ int   sIdx[4][64];
    __shared__ float sExT[4][4][72];           // [wave][head][edge] padded vs bank conflict

    const int tid = threadIdx.x;
    const int lane = tid & 63;
    const int w = tid >> 6;
    const int n = blockIdx.x * 4 + w;
    if (n >= n_nodes) return;                  // no block-level sync in this kernel

    const int rs = rowptr[n];
    const int deg = degarr[n];
    const float4 ad4 = *(const float4*)(AD + n * 4);

    // pass 1: per-head max over edges (lane-parallel, chunked by 64)
    float m0 = -1e30f, m1 = -1e30f, m2 = -1e30f, m3 = -1e30f;
    for (int base = 0; base < deg; base += 64) {
        int idx = base + lane;
        if (idx < deg) {
            int s = csr_src[rs + idx];
            float4 a = *(const float4*)(AS + s * 4);
            m0 = fmaxf(m0, lrelu_(a.x + ad4.x));
            m1 = fmaxf(m1, lrelu_(a.y + ad4.y));
            m2 = fmaxf(m2, lrelu_(a.z + ad4.z));
            m3 = fmaxf(m3, lrelu_(a.w + ad4.w));
        }
    }
#pragma unroll
    for (int off = 32; off > 0; off >>= 1) {
        m0 = fmaxf(m0, __shfl_xor(m0, off));
        m1 = fmaxf(m1, __shfl_xor(m1, off));
        m2 = fmaxf(m2, __shfl_xor(m2, off));
        m3 = fmaxf(m3, __shfl_xor(m3, off));
    }

    const int half = lane >> 5;                // 0: even edges, 1: odd edges
    const int l32 = lane & 31;
    const int ch0 = l32 * 8;                   // 8 channels per lane (of 32)
    const int h = l32 >> 3;                    // head of these channels

    float4 acc0 = make_float4(0.f, 0.f, 0.f, 0.f);
    float4 acc1 = make_float4(0.f, 0.f, 0.f, 0.f);
    float d0 = 0.f, d1 = 0.f, d2 = 0.f, d3 = 0.f;

    for (int base = 0; base < deg; base += 64) {
        int cnt = deg - base; if (cnt > 64) cnt = 64;
        // stage: lane e -> src idx + un-normalized exp per head
        int idx = base + lane;
        int sv = 0;
        float e0 = 0.f, e1 = 0.f, e2 = 0.f, e3 = 0.f;
        if (idx < deg) {
            sv = csr_src[rs + idx];
            float4 a = *(const float4*)(AS + sv * 4);
            e0 = __expf(lrelu_(a.x + ad4.x) - m0);
            e1 = __expf(lrelu_(a.y + ad4.y) - m1);
            e2 = __expf(lrelu_(a.z + ad4.z) - m2);
            e3 = __expf(lrelu_(a.w + ad4.w) - m3);
        }
        sIdx[w][lane] = sv;
        sExT[w][0][lane] = e0; sExT[w][1][lane] = e1;
        sExT[w][2][lane] = e2; sExT[w][3][lane] = e3;
        d0 += e0; d1 += e1; d2 += e2; d3 += e3;
        __builtin_amdgcn_wave_barrier();

        // accumulate: 2 edges per iteration (lanes 0-31: edge j, 32-63: edge j+1)
        int cpad = (cnt + 1) & ~1;
        for (int j = 0; j < cpad; j += 2) {
            int jj = j + half;
            int s = sIdx[w][jj];
            float e = sExT[w][h][jj];
            const uint4 q = *(const uint4*)(XLb + (size_t)s * 256 + ch0);
            acc0.x += e * bflo(q.x); acc0.y += e * bfhi(q.x);
            acc0.z += e * bflo(q.y); acc0.w += e * bfhi(q.y);
            acc1.x += e * bflo(q.z); acc1.y += e * bfhi(q.z);
            acc1.z += e * bflo(q.w); acc1.w += e * bfhi(q.w);
        }
        __builtin_amdgcn_wave_barrier();
    }

    // fold the two edge-halves
    acc0.x += __shfl_xor(acc0.x, 32); acc0.y += __shfl_xor(acc0.y, 32);
    acc0.z += __shfl_xor(acc0.z, 32); acc0.w += __shfl_xor(acc0.w, 32);
    acc1.x += __shfl_xor(acc1.x, 32); acc1.y += __shfl_xor(acc1.y, 32);
    acc1.z += __shfl_xor(acc1.z, 32); acc1.w += __shfl_xor(acc1.w, 32);
    // denominator per head
#pragma unroll
    for (int off = 32; off > 0; off >>= 1) {
        d0 += __shfl_xor(d0, off); d1 += __shfl_xor(d1, off);
        d2 += __shfl_xor(d2, off); d3 += __shfl_xor(d3, off);
    }
    float den = (h == 0) ? d0 : (h == 1) ? d1 : (h == 2) ? d2 : d3;
    float inv = 1.f / (den + 1e-16f);

    if (lane < 32) {
        size_t o = (size_t)n * 256 + ch0;
        uint4 hq = *(const uint4*)(Hlinb + o);
        float4 cba = *(const float4*)(cb + ch0);
        float4 cbb = *(const float4*)(cb + ch0 + 4);
        float v0 = elu_(acc0.x * inv + cba.x + bflo(hq.x));
        float v1 = elu_(acc0.y * inv + cba.y + bfhi(hq.x));
        float v2 = elu_(acc0.z * inv + cba.z + bflo(hq.y));
        float v3 = elu_(acc0.w * inv + cba.w + bfhi(hq.y));
        float v4 = elu_(acc1.x * inv + cbb.x + bflo(hq.z));
        float v5 = elu_(acc1.y * inv + cbb.y + bfhi(hq.z));
        float v6 = elu_(acc1.z * inv + cbb.z + bflo(hq.w));
        float v7 = elu_(acc1.w * inv + cbb.w + bfhi(hq.w));
        uint4 ov;
        ov.x = (unsigned)(unsigned short)f2bf(v0) | ((unsigned)(unsigned short)f2bf(v1) << 16);
        ov.y = (unsigned)(unsigned short)f2bf(v2) | ((unsigned)(unsigned short)f2bf(v3) << 16);
        ov.z = (unsigned)(unsigned short)f2bf(v4) | ((unsigned)(unsigned short)f2bf(v5) << 16);
        ov.w = (unsigned)(unsigned short)f2bf(v6) | ((unsigned)(unsigned short)f2bf(v7) << 16);
        *(uint4*)(Hb + o) = ov;
    }
}

// ---------------- layer 2 projections ----------------

__global__ __launch_bounds__(256) void l2_prep(const short* __restrict__ Hin,
                                               const float* __restrict__ cW2,
                                               const float* __restrict__ lW2,
                                               const float* __restrict__ lb2,
                                               float* __restrict__ XL2,
                                               float* __restrict__ LIN2, int n_nodes) {
    int n = (blockIdx.x * blockDim.x + threadIdx.x) >> 6;
    int lane = threadIdx.x & 63;
    if (n >= n_nodes) return;
    uint2 q = *(const uint2*)(Hin + (size_t)n * 256 + lane * 4);
    float hk0 = bflo(q.x), hk1 = bfhi(q.x);
    float hk2 = bflo(q.y), hk3 = bfhi(q.y);
    int k = lane * 4;
    float4 w0 = *(const float4*)(cW2 + (k + 0) * 4);
    float4 w1 = *(const float4*)(cW2 + (k + 1) * 4);
    float4 w2 = *(const float4*)(cW2 + (k + 2) * 4);
    float4 w3 = *(const float4*)(cW2 + (k + 3) * 4);
    float a0 = hk0 * w0.x + hk1 * w1.x + hk2 * w2.x + hk3 * w3.x;
    float a1 = hk0 * w0.y + hk1 * w1.y + hk2 * w2.y + hk3 * w3.y;
    float a2 = hk0 * w0.z + hk1 * w1.z + hk2 * w2.z + hk3 * w3.z;
    float a3 = hk0 * w0.w + hk1 * w1.w + hk2 * w2.w + hk3 * w3.w;
    float4 lw = make_float4(lW2[k], lW2[k + 1], lW2[k + 2], lW2[k + 3]);
    float al = hk0 * lw.x + hk1 * lw.y + hk2 * lw.z + hk3 * lw.w;
#pragma unroll
    for (int off = 32; off > 0; off >>= 1) {
        a0 += __shfl_xor(a0, off); a1 += __shfl_xor(a1, off);
        a2 += __shfl_xor(a2, off); a3 += __shfl_xor(a3, off);
        al += __shfl_xor(al, off);
    }
    if (lane == 0) {
        float4 o = make_float4(a0, a1, a2, a3);
        *(float4*)(XL2 + n * 4) = o;
        LIN2[n] = al + lb2[0];
    }
}

// ---------------- layer 2 aggregation ----------------

__global__ __launch_bounds__(256) void l2_agg(const float* __restrict__ XL2,
                                              const float* __restrict__ LIN2,
                                              const float* __restrict__ cas2,
                                              const float* __restrict__ cad2,
                                              const float* __restrict__ cb2,
                                              const int* __restrict__ rowptr,
                                              const int* __restrict__ degarr,
                                              const int* __restrict__ csr_src,
                                              float* __restrict__ out, int n_nodes) {
    int n = (blockIdx.x * blockDim.x + threadIdx.x) >> 6;
    int lane = threadIdx.x & 63;
    if (n >= n_nodes) return;
    int rs = rowptr[n], re = rs + degarr[n];
    float4 xn = *(const float4*)(XL2 + n * 4);
    float cs0 = cas2[0], cs1 = cas2[1], cs2 = cas2[2], cs3 = cas2[3];
    float cd0 = cad2[0], cd1 = cad2[1], cd2 = cad2[2], cd3 = cad2[3];
    float ad0 = xn.x * cd0, ad1 = xn.y * cd1, ad2 = xn.z * cd2, ad3 = xn.w * cd3;

    float m0 = -1e30f, m1 = -1e30f, m2 = -1e30f, m3 = -1e30f;
    for (int i = rs + lane; i < re; i += 64) {
        int s = csr_src[i];
        float4 xs = *(const float4*)(XL2 + s * 4);
        m0 = fmaxf(m0, lrelu_(xs.x * cs0 + ad0));
        m1 = fmaxf(m1, lrelu_(xs.y * cs1 + ad1));
        m2 = fmaxf(m2, lrelu_(xs.z * cs2 + ad2));
        m3 = fmaxf(m3, lrelu_(xs.w * cs3 + ad3));
    }
#pragma unroll
    for (int off = 32; off > 0; off >>= 1) {
        m0 = fmaxf(m0, __shfl_xor(m0, off));
        m1 = fmaxf(m1, __shfl_xor(m1, off));
        m2 = fmaxf(m2, __shfl_xor(m2, off));
        m3 = fmaxf(m3, __shfl_xor(m3, off));
    }

    float d0 = 0.f, d1 = 0.f, d2 = 0.f, d3 = 0.f;
    float t0 = 0.f, t1 = 0.f, t2 = 0.f, t3 = 0.f;
    for (int i = rs + lane; i < re; i += 64) {
        int s = csr_src[i];
        float4 xs = *(const float4*)(XL2 + s * 4);
        float e0 = __expf(lrelu_(xs.x * cs0 + ad0) - m0);
        float e1 = __expf(lrelu_(xs.y * cs1 + ad1) - m1);
        float e2 = __expf(lrelu_(xs.z * cs2 + ad2) - m2);
        float e3 = __expf(lrelu_(xs.w * cs3 + ad3) - m3);
        d0 += e0; d1 += e1; d2 += e2; d3 += e3;
        t0 += e0 * xs.x; t1 += e1 * xs.y; t2 += e2 * xs.z; t3 += e3 * xs.w;
    }
#pragma unroll
    for (int off = 32; off > 0; off >>= 1) {
        d0 += __shfl_xor(d0, off); d1 += __shfl_xor(d1, off);
        d2 += __shfl_xor(d2, off); d3 += __shfl_xor(d3, off);
        t0 += __shfl_xor(t0, off); t1 += __shfl_xor(t1, off);
        t2 += __shfl_xor(t2, off); t3 += __shfl_xor(t3, off);
    }
    if (lane == 0) {
        float r = 0.25f * (t0 / (d0 + 1e-16f) + t1 / (d1 + 1e-16f) +
                           t2 / (d2 + 1e-16f) + t3 / (d3 + 1e-16f));
        out[n] = r + cb2[0] + LIN2[n];
    }
}

// ---------------- launch ----------------

extern "C" void kernel_launch(void* const* d_in, const int* in_sizes, int n_in,
                              void* d_out, int out_size, void* d_ws, size_t ws_size,
                              hipStream_t stream) {
    const float* x    = (const float*)d_in[0];
    const int*   ei   = (const int*)d_in[1];
    const float* cW0  = (const float*)d_in[3];
    const float* cas0 = (const float*)d_in[4];
    const float* cad0 = (const float*)d_in[5];
    const float* cb0  = (const float*)d_in[6];
    const float* lW0  = (const float*)d_in[7];
    const float* lb0  = (const float*)d_in[8];
    const float* cW1  = (const float*)d_in[9];
    const float* cas1 = (const float*)d_in[10];
    const float* cad1 = (const float*)d_in[11];
    const float* cb1  = (const float*)d_in[12];
    const float* lW1  = (const float*)d_in[13];
    const float* lb1  = (const float*)d_in[14];
    const float* cW2  = (const float*)d_in[15];
    const float* cas2 = (const float*)d_in[16];
    const float* cad2 = (const float*)d_in[17];
    const float* cb2  = (const float*)d_in[18];
    const float* lW2  = (const float*)d_in[19];
    const float* lb2  = (const float*)d_in[20];
    float* out = (float*)d_out;

    // workspace layout (~122 MB)
    short* xb    = (short*)d_ws;                 // 6.4M bf16
    short* XLb   = xb + 6400000;                 // 12.8M bf16
    short* HAb   = XLb + 12800000;
    short* HBb   = HAb + 12800000;
    short* Hlinb = HBb + 12800000;               // 12.8M bf16
    short* Wt0   = Hlinb + 12800000;             // 512*128
    short* Wt1   = Wt0 + 65536;                  // 512*256
    float* AS    = (float*)(Wt1 + 131072);
    float* AD    = AS + 200000;
    float* XL2   = AD + 200000;
    float* LIN2  = XL2 + 200000;
    int* deg     = (int*)(LIN2 + NN);            // [NN]
    int* cursor  = deg + NN;                     // [NN]
    int* gcnt    = cursor + NN;                  // [4]
    int* rowptr  = gcnt + 4;                     // [NN]
    int* csr_src = rowptr + NN;                  // [ET_]

    dim3 b256(256);
    dim3 gEdges((ET_ + 255) / 256);
    dim3 gNodesWave((NN + 3) / 4);

    // CSR build: zero deg+cursor+gcnt in one memset (contiguous)
    hipMemsetAsync(deg, 0, (2 * (size_t)NN + 4) * sizeof(int), stream);
    prep_all<<<dim3(7018), b256, 0, stream>>>(x, cW0, lW0, cW1, lW1, xb, Wt0, Wt1);
    degree_k<<<gEdges, b256, 0, stream>>>(ei, deg);
    alloc_scan<<<dim3((NN + 1023) / 1024), dim3(1024), 0, stream>>>(deg, rowptr, gcnt, NN);
    scatter_k<<<gEdges, b256, 0, stream>>>(ei, rowptr, cursor, csr_src);

    dim3 gemmGrid((NN + 127) / 128, 4);

    // layer 0
    gemm_bf16<<<gemmGrid, b256, 0, stream>>>(xb, Wt0, lb0, XLb, Hlinb, NN, 128);
    attn_prep<<<gNodesWave, b256, 0, stream>>>(XLb, cas0, cad0, AS, AD, NN);
    gat_agg<<<gNodesWave, b256, 0, stream>>>(XLb, AS, AD, rowptr, deg, csr_src, cb0, Hlinb, HAb, NN);

    // layer 1
    gemm_bf16<<<gemmGrid, b256, 0, stream>>>(HAb, Wt1, lb1, XLb, Hlinb, NN, 256);
    attn_prep<<<gNodesWave, b256, 0, stream>>>(XLb, cas1, cad1, AS, AD, NN);
    gat_agg<<<gNodesWave, b256, 0, stream>>>(XLb, AS, AD, rowptr, deg, csr_src, cb1, Hlinb, HBb, NN);

    // layer 2
    l2_prep<<<gNodesWave, b256, 0, stream>>>(HBb, cW2, lW2, lb2, XL2, LIN2, NN);
    l2_agg<<<gNodesWave, b256, 0, stream>>>(XL2, LIN2, cas2, cad2, cb2, rowptr, deg, csr_src, out, NN);
}

// Round 6
// 506.956 us; speedup vs baseline: 1.8516x; 1.0088x over previous
//
#include <hip/hip_runtime.h>
#include <cstddef>
#include <cstdint>

#define NN 50000
#define EE 800000
#define ET_ (EE + NN)

typedef __attribute__((ext_vector_type(8))) short bf16x8;
typedef __attribute__((ext_vector_type(4))) float f32x4;

__device__ __forceinline__ float lrelu_(float x) { return x > 0.f ? x : 0.2f * x; }
__device__ __forceinline__ float elu_(float x)   { return x > 0.f ? x : (__expf(x) - 1.f); }
__device__ __forceinline__ short f2bf(float f) {
    unsigned u = __float_as_uint(f);
    unsigned r = (u + 0x7fffu + ((u >> 16) & 1u)) >> 16;
    return (short)r;
}
__device__ __forceinline__ float bflo(unsigned u) { return __uint_as_float(u << 16); }
__device__ __forceinline__ float bfhi(unsigned u) { return __uint_as_float(u & 0xffff0000u); }

#define GL16(gp, lp) __builtin_amdgcn_global_load_lds( \
    (const __attribute__((address_space(1))) unsigned int*)(gp), \
    (__attribute__((address_space(3))) unsigned int*)(lp), 16, 0, 0)

// ---------------- CSR build ----------------

__global__ __launch_bounds__(256) void degree_k(const int* __restrict__ ei, int* __restrict__ deg) {
    int e = blockIdx.x * blockDim.x + threadIdx.x;
    if (e >= ET_) return;
    int d = (e < EE) ? ei[EE + e] : (e - EE);
    atomicAdd(&deg[d], 1);
}

__global__ __launch_bounds__(1024) void alloc_scan(const int* __restrict__ deg, int* __restrict__ rowptr,
                                                   int* __restrict__ gcnt, int n) {
    __shared__ int s[1024];
    __shared__ int basesh;
    int tid = threadIdx.x;
    int gid = blockIdx.x * 1024 + tid;
    int v = (gid < n) ? deg[gid] : 0;
    s[tid] = v;
    __syncthreads();
    for (int off = 1; off < 1024; off <<= 1) {
        int t = (tid >= off) ? s[tid - off] : 0;
        __syncthreads();
        s[tid] += t;
        __syncthreads();
    }
    if (tid == 1023) basesh = atomicAdd(gcnt, s[1023]);
    __syncthreads();
    if (gid < n) rowptr[gid] = basesh + s[tid] - v;
}

__global__ __launch_bounds__(256) void scatter_k(const int* __restrict__ ei,
                                                 const int* __restrict__ rowptr,
                                                 int* __restrict__ cursor,
                                                 int* __restrict__ csr_src) {
    int e = blockIdx.x * blockDim.x + threadIdx.x;
    if (e >= ET_) return;
    int s, d;
    if (e < EE) { s = ei[e]; d = ei[EE + e]; } else { s = e - EE; d = e - EE; }
    int pos = atomicAdd(&cursor[d], 1);
    csr_src[rowptr[d] + pos] = s;
}

// ---------------- fused dtype prep: x -> bf16, pack Wt0/Wt1 ----------------

__global__ __launch_bounds__(256) void prep_all(const float* __restrict__ x,
                                                const float* __restrict__ cW0, const float* __restrict__ lW0,
                                                const float* __restrict__ cW1, const float* __restrict__ lW1,
                                                short* __restrict__ xb, short* __restrict__ Wt0,
                                                short* __restrict__ Wt1) {
    int i = blockIdx.x * 256 + threadIdx.x;
    if (i < 1600000) {
        float4 v = *(const float4*)(x + (size_t)i * 4);
        short4 o;
        o.x = f2bf(v.x); o.y = f2bf(v.y); o.z = f2bf(v.z); o.w = f2bf(v.w);
        *(short4*)(xb + (size_t)i * 4) = o;
        return;
    }
    i -= 1600000;
    if (i < 512 * 128) {
        int n = i >> 7, k = i & 127;
        float v = (n < 256) ? cW0[k * 256 + n] : lW0[k * 256 + (n - 256)];
        Wt0[i] = f2bf(v);
        return;
    }
    i -= 512 * 128;
    if (i < 512 * 256) {
        int n = i >> 8, k = i & 255;
        float v = (n < 256) ? cW1[k * 256 + n] : lW1[k * 256 + (n - 256)];
        Wt1[i] = f2bf(v);
    }
}

// ---------------- bf16 MFMA GEMM, double-buffered: out[M,512] = A[M,K] @ Wt^T ----------------

__global__ __launch_bounds__(256) void gemm_bf16(const short* __restrict__ A,
                                                 const short* __restrict__ Wt,
                                                 const float* __restrict__ biasLin,
                                                 short* __restrict__ XLb,
                                                 short* __restrict__ Hlinb,
                                                 int M, int K) {
    __shared__ short As[2][128 * 32];
    __shared__ short Bs[2][128 * 32];
    const int tid = threadIdx.x;
    const int lane = tid & 63;
    const int wid = tid >> 6;
    const int bm = blockIdx.x * 128;
    const int col0 = blockIdx.y * 128;
    const int wr = wid >> 1, wc = wid & 1;

    f32x4 acc[4][4];
#pragma unroll
    for (int i = 0; i < 4; ++i)
#pragma unroll
        for (int j = 0; j < 4; ++j) acc[i][j] = (f32x4){0.f, 0.f, 0.f, 0.f};

    const int lrow = lane & 15, lk = lane >> 4;

    auto stage = [&](int b, int kk) {
#pragma unroll
        for (int it = 0; it < 2; ++it) {
            const int flat = tid + it * 256;
            const int row = flat >> 2, slot = flat & 3;
            const int ss = slot ^ (row & 3);      // pre-swizzled source chunk
            int ar = bm + row; ar = (ar < M) ? ar : (M - 1);
            GL16(A + (size_t)ar * K + kk + ss * 8, &As[b][flat * 8]);
            GL16(Wt + (size_t)(col0 + row) * K + kk + ss * 8, &Bs[b][flat * 8]);
        }
    };

    stage(0, 0);
    int cur = 0;
    for (int k0 = 0; k0 < K; k0 += 32) {
        __syncthreads();                       // buf[cur] staged; prev reads done
        if (k0 + 32 < K) stage(cur ^ 1, k0 + 32);   // prefetch overlaps compute
        bf16x8 af[4], bfr[4];
#pragma unroll
        for (int mi = 0; mi < 4; ++mi) {
            const int r = wr * 64 + mi * 16 + lrow;
            af[mi] = *(const bf16x8*)(&As[cur][(r * 4 + (lk ^ (r & 3))) * 8]);
        }
#pragma unroll
        for (int ni = 0; ni < 4; ++ni) {
            const int c = wc * 64 + ni * 16 + lrow;
            bfr[ni] = *(const bf16x8*)(&Bs[cur][(c * 4 + (lk ^ (c & 3))) * 8]);
        }
#pragma unroll
        for (int mi = 0; mi < 4; ++mi)
#pragma unroll
            for (int ni = 0; ni < 4; ++ni)
                acc[mi][ni] = __builtin_amdgcn_mfma_f32_16x16x32_bf16(af[mi], bfr[ni], acc[mi][ni], 0, 0, 0);
        cur ^= 1;
    }

    const int lrow4 = (lane >> 4) * 4;
    const bool isLin = (col0 >= 256);
#pragma unroll
    for (int mi = 0; mi < 4; ++mi) {
#pragma unroll
        for (int ni = 0; ni < 4; ++ni) {
            const int col = col0 + wc * 64 + ni * 16 + (lane & 15);
#pragma unroll
            for (int rr = 0; rr < 4; ++rr) {
                const int grow = bm + wr * 64 + mi * 16 + lrow4 + rr;
                if (grow < M) {
                    float v = acc[mi][ni][rr];
                    if (isLin) {
                        const int c = col - 256;
                        Hlinb[(size_t)grow * 256 + c] = f2bf(v + biasLin[c]);
                    } else {
                        XLb[(size_t)grow * 256 + col] = f2bf(v);
                    }
                }
            }
        }
    }
}

// ---------------- attention prep: a_s/a_d per node per head ----------------

__global__ __launch_bounds__(256) void attn_prep(const short* __restrict__ XLb,
                                                 const float* __restrict__ cas,
                                                 const float* __restrict__ cad,
                                                 float* __restrict__ AS,
                                                 float* __restrict__ AD, int n_nodes) {
    int n = (blockIdx.x * blockDim.x + threadIdx.x) >> 6;
    int lane = threadIdx.x & 63;
    if (n >= n_nodes) return;
    uint2 q = *(const uint2*)(XLb + (size_t)n * 256 + lane * 4);
    float x0 = bflo(q.x), x1 = bfhi(q.x);
    float x2 = bflo(q.y), x3 = bfhi(q.y);
    float4 sv = *(const float4*)(cas + lane * 4);
    float4 dv = *(const float4*)(cad + lane * 4);
    float ps = x0 * sv.x + x1 * sv.y + x2 * sv.z + x3 * sv.w;
    float pd = x0 * dv.x + x1 * dv.y + x2 * dv.z + x3 * dv.w;
#pragma unroll
    for (int off = 1; off < 16; off <<= 1) {
        ps += __shfl_xor(ps, off);
        pd += __shfl_xor(pd, off);
    }
    if ((lane & 15) == 0) {
        AS[n * 4 + (lane >> 4)] = ps;
        AD[n * 4 + (lane >> 4)] = pd;
    }
}

// ---------------- GAT aggregation: wave per node, lane per edge ----------------
// deg<=64 fast path keeps scores in registers (one gather pass).
// If XL2 != null (layer 1): fuse the layer-2 projections, skip writing Hb.

__global__ __launch_bounds__(256) void gat_agg(const short* __restrict__ XLb,
                                               const float* __restrict__ AS,
                                               const float* __restrict__ AD,
                                               const int* __restrict__ rowptr,
                                               const int* __restrict__ degarr,
                                               const int* __restrict__ csr_src,
                                               const float* __restrict__ cb,
                                               const short* __restrict__ Hlinb,
                                               short* __restrict__ Hb,
                                               const float* __restrict__ cW2,
                                               const float* __restrict__ lW2,
                                               const float* __restrict__ lb2,
                                               float* __restrict__ XL2,
                                               float* __restrict__ LIN2,
                                               int n_nodes) {
    __shared__ int   sIdx[4][64];
    __shared__ float sExT[4][4][72];           // [wave][head][edge] padded

    const int tid = threadIdx.x;
    const int lane = tid & 63;
    const int w = tid >> 6;
    const int n = blockIdx.x * 4 + w;
    if (n >= n_nodes) return;                  // no block-level sync in this kernel

    const int rs = rowptr[n];
    const int deg = degarr[n];
    const float4 ad4 = *(const float4*)(AD + n * 4);

    const int half = lane >> 5;
    const int l32 = lane & 31;
    const int ch0 = l32 * 8;
    const int h = l32 >> 3;

    float4 acc0 = make_float4(0.f, 0.f, 0.f, 0.f);
    float4 acc1 = make_float4(0.f, 0.f, 0.f, 0.f);
    float d0 = 0.f, d1 = 0.f, d2 = 0.f, d3 = 0.f;

    if (deg <= 64) {
        // ---- fast path: scores stay in registers across max+exp ----
        int sv = 0;
        float c0 = -1e30f, c1 = -1e30f, c2 = -1e30f, c3 = -1e30f;
        if (lane < deg) {
            sv = csr_src[rs + lane];
            float4 a = *(const float4*)(AS + sv * 4);
            c0 = lrelu_(a.x + ad4.x); c1 = lrelu_(a.y + ad4.y);
            c2 = lrelu_(a.z + ad4.z); c3 = lrelu_(a.w + ad4.w);
        }
        float m0 = c0, m1 = c1, m2 = c2, m3 = c3;
#pragma unroll
        for (int off = 32; off > 0; off >>= 1) {
            m0 = fmaxf(m0, __shfl_xor(m0, off));
            m1 = fmaxf(m1, __shfl_xor(m1, off));
            m2 = fmaxf(m2, __shfl_xor(m2, off));
            m3 = fmaxf(m3, __shfl_xor(m3, off));
        }
        float e0 = 0.f, e1 = 0.f, e2 = 0.f, e3 = 0.f;
        if (lane < deg) {
            e0 = __expf(c0 - m0); e1 = __expf(c1 - m1);
            e2 = __expf(c2 - m2); e3 = __expf(c3 - m3);
        }
        sIdx[w][lane] = sv;
        sExT[w][0][lane] = e0; sExT[w][1][lane] = e1;
        sExT[w][2][lane] = e2; sExT[w][3][lane] = e3;
        d0 = e0; d1 = e1; d2 = e2; d3 = e3;
        __builtin_amdgcn_wave_barrier();

        int cpad = (deg + 1) & ~1;
        for (int j = 0; j < cpad; j += 2) {
            int jj = j + half;
            int s = sIdx[w][jj];
            float e = sExT[w][h][jj];
            const uint4 q = *(const uint4*)(XLb + (size_t)s * 256 + ch0);
            acc0.x += e * bflo(q.x); acc0.y += e * bfhi(q.x);
            acc0.z += e * bflo(q.y); acc0.w += e * bfhi(q.y);
            acc1.x += e * bflo(q.z); acc1.y += e * bfhi(q.z);
            acc1.z += e * bflo(q.w); acc1.w += e * bfhi(q.w);
        }
    } else {
        // ---- generic chunked path (rare) ----
        float m0 = -1e30f, m1 = -1e30f, m2 = -1e30f, m3 = -1e30f;
        for (int base = 0; base < deg; base += 64) {
            int idx = base + lane;
            if (idx < deg) {
                int s = csr_src[rs + idx];
                float4 a = *(const float4*)(AS + s * 4);
                m0 = fmaxf(m0, lrelu_(a.x + ad4.x));
                m1 = fmaxf(m1, lrelu_(a.y + ad4.y));
                m2 = fmaxf(m2, lrelu_(a.z + ad4.z));
                m3 = fmaxf(m3, lrelu_(a.w + ad4.w));
            }
        }
#pragma unroll
        for (int off = 32; off > 0; off >>= 1) {
            m0 = fmaxf(m0, __shfl_xor(m0, off));
            m1 = fmaxf(m1, __shfl_xor(m1, off));
            m2 = fmaxf(m2, __shfl_xor(m2, off));
            m3 = fmaxf(m3, __shfl_xor(m3, off));
        }
        for (int base = 0; base < deg; base += 64) {
            int cnt = deg - base; if (cnt > 64) cnt = 64;
            int idx = base + lane;
            int sv = 0;
            float e0 = 0.f, e1 = 0.f, e2 = 0.f, e3 = 0.f;
            if (idx < deg) {
                sv = csr_src[rs + idx];
                float4 a = *(const float4*)(AS + sv * 4);
                e0 = __expf(lrelu_(a.x + ad4.x) - m0);
                e1 = __expf(lrelu_(a.y + ad4.y) - m1);
                e2 = __expf(lrelu_(a.z + ad4.z) - m2);
                e3 = __expf(lrelu_(a.w + ad4.w) - m3);
            }
            sIdx[w][lane] = sv;
            sExT[w][0][lane] = e0; sExT[w][1][lane] = e1;
            sExT[w][2][lane] = e2; sExT[w][3][lane] = e3;
            d0 += e0; d1 += e1; d2 += e2; d3 += e3;
            __builtin_amdgcn_wave_barrier();
            int cpad = (cnt + 1) & ~1;
            for (int j = 0; j < cpad; j += 2) {
                int jj = j + half;
                int s = sIdx[w][jj];
                float e = sExT[w][h][jj];
                const uint4 q = *(const uint4*)(XLb + (size_t)s * 256 + ch0);
                acc0.x += e * bflo(q.x); acc0.y += e * bfhi(q.x);
                acc0.z += e * bflo(q.y); acc0.w += e * bfhi(q.y);
                acc1.x += e * bflo(q.z); acc1.y += e * bfhi(q.z);
                acc1.z += e * bflo(q.w); acc1.w += e * bfhi(q.w);
            }
            __builtin_amdgcn_wave_barrier();
        }
    }

    // fold edge-halves + reduce denominators
    acc0.x += __shfl_xor(acc0.x, 32); acc0.y += __shfl_xor(acc0.y, 32);
    acc0.z += __shfl_xor(acc0.z, 32); acc0.w += __shfl_xor(acc0.w, 32);
    acc1.x += __shfl_xor(acc1.x, 32); acc1.y += __shfl_xor(acc1.y, 32);
    acc1.z += __shfl_xor(acc1.z, 32); acc1.w += __shfl_xor(acc1.w, 32);
#pragma unroll
    for (int off = 32; off > 0; off >>= 1) {
        d0 += __shfl_xor(d0, off); d1 += __shfl_xor(d1, off);
        d2 += __shfl_xor(d2, off); d3 += __shfl_xor(d3, off);
    }
    float den = (h == 0) ? d0 : (h == 1) ? d1 : (h == 2) ? d2 : d3;
    float inv = 1.f / (den + 1e-16f);

    float v0 = 0.f, v1 = 0.f, v2 = 0.f, v3 = 0.f, v4 = 0.f, v5 = 0.f, v6 = 0.f, v7 = 0.f;
    if (lane < 32) {
        size_t o = (size_t)n * 256 + ch0;
        uint4 hq = *(const uint4*)(Hlinb + o);
        float4 cba = *(const float4*)(cb + ch0);
        float4 cbb = *(const float4*)(cb + ch0 + 4);
        v0 = elu_(acc0.x * inv + cba.x + bflo(hq.x));
        v1 = elu_(acc0.y * inv + cba.y + bfhi(hq.x));
        v2 = elu_(acc0.z * inv + cba.z + bflo(hq.y));
        v3 = elu_(acc0.w * inv + cba.w + bfhi(hq.y));
        v4 = elu_(acc1.x * inv + cbb.x + bflo(hq.z));
        v5 = elu_(acc1.y * inv + cbb.y + bfhi(hq.z));
        v6 = elu_(acc1.z * inv + cbb.z + bflo(hq.w));
        v7 = elu_(acc1.w * inv + cbb.w + bfhi(hq.w));
    }

    if (XL2 != nullptr) {
        // fused layer-2 projections: xl2[n][h2] = h . cW2[:,h2], lin2 = h . lW2 + lb2
        float p0 = 0.f, p1 = 0.f, p2 = 0.f, p3 = 0.f, pl = 0.f;
        if (lane < 32) {
            const float vv[8] = {v0, v1, v2, v3, v4, v5, v6, v7};
            float4 lwa = *(const float4*)(lW2 + ch0);
            float4 lwb = *(const float4*)(lW2 + ch0 + 4);
            const float lw[8] = {lwa.x, lwa.y, lwa.z, lwa.w, lwb.x, lwb.y, lwb.z, lwb.w};
#pragma unroll
            for (int j = 0; j < 8; ++j) {
                float4 wv = *(const float4*)(cW2 + (ch0 + j) * 4);
                p0 += vv[j] * wv.x; p1 += vv[j] * wv.y;
                p2 += vv[j] * wv.z; p3 += vv[j] * wv.w;
                pl += vv[j] * lw[j];
            }
        }
#pragma unroll
        for (int off = 16; off > 0; off >>= 1) {
            p0 += __shfl_xor(p0, off); p1 += __shfl_xor(p1, off);
            p2 += __shfl_xor(p2, off); p3 += __shfl_xor(p3, off);
            pl += __shfl_xor(pl, off);
        }
        if (lane == 0) {
            *(float4*)(XL2 + n * 4) = make_float4(p0, p1, p2, p3);
            LIN2[n] = pl + lb2[0];
        }
    } else if (lane < 32) {
        size_t o = (size_t)n * 256 + ch0;
        uint4 ov;
        ov.x = (unsigned)(unsigned short)f2bf(v0) | ((unsigned)(unsigned short)f2bf(v1) << 16);
        ov.y = (unsigned)(unsigned short)f2bf(v2) | ((unsigned)(unsigned short)f2bf(v3) << 16);
        ov.z = (unsigned)(unsigned short)f2bf(v4) | ((unsigned)(unsigned short)f2bf(v5) << 16);
        ov.w = (unsigned)(unsigned short)f2bf(v6) | ((unsigned)(unsigned short)f2bf(v7) << 16);
        *(uint4*)(Hb + o) = ov;
    }
}

// ---------------- layer 2 aggregation ----------------

__global__ __launch_bounds__(256) void l2_agg(const float* __restrict__ XL2,
                                              const float* __restrict__ LIN2,
                                              const float* __restrict__ cas2,
                                              const float* __restrict__ cad2,
                                              const float* __restrict__ cb2,
                                              const int* __restrict__ rowptr,
                                              const int* __restrict__ degarr,
                                              const int* __restrict__ csr_src,
                                              float* __restrict__ out, int n_nodes) {
    int n = (blockIdx.x * blockDim.x + threadIdx.x) >> 6;
    int lane = threadIdx.x & 63;
    if (n >= n_nodes) return;
    int rs = rowptr[n], re = rs + degarr[n];
    float4 xn = *(const float4*)(XL2 + n * 4);
    float cs0 = cas2[0], cs1 = cas2[1], cs2 = cas2[2], cs3 = cas2[3];
    float cd0 = cad2[0], cd1 = cad2[1], cd2 = cad2[2], cd3 = cad2[3];
    float ad0 = xn.x * cd0, ad1 = xn.y * cd1, ad2 = xn.z * cd2, ad3 = xn.w * cd3;

    float m0 = -1e30f, m1 = -1e30f, m2 = -1e30f, m3 = -1e30f;
    for (int i = rs + lane; i < re; i += 64) {
        int s = csr_src[i];
        float4 xs = *(const float4*)(XL2 + s * 4);
        m0 = fmaxf(m0, lrelu_(xs.x * cs0 + ad0));
        m1 = fmaxf(m1, lrelu_(xs.y * cs1 + ad1));
        m2 = fmaxf(m2, lrelu_(xs.z * cs2 + ad2));
        m3 = fmaxf(m3, lrelu_(xs.w * cs3 + ad3));
    }
#pragma unroll
    for (int off = 32; off > 0; off >>= 1) {
        m0 = fmaxf(m0, __shfl_xor(m0, off));
        m1 = fmaxf(m1, __shfl_xor(m1, off));
        m2 = fmaxf(m2, __shfl_xor(m2, off));
        m3 = fmaxf(m3, __shfl_xor(m3, off));
    }

    float d0 = 0.f, d1 = 0.f, d2 = 0.f, d3 = 0.f;
    float t0 = 0.f, t1 = 0.f, t2 = 0.f, t3 = 0.f;
    for (int i = rs + lane; i < re; i += 64) {
        int s = csr_src[i];
        float4 xs = *(const float4*)(XL2 + s * 4);
        float e0 = __expf(lrelu_(xs.x * cs0 + ad0) - m0);
        float e1 = __expf(lrelu_(xs.y * cs1 + ad1) - m1);
        float e2 = __expf(lrelu_(xs.z * cs2 + ad2) - m2);
        float e3 = __expf(lrelu_(xs.w * cs3 + ad3) - m3);
        d0 += e0; d1 += e1; d2 += e2; d3 += e3;
        t0 += e0 * xs.x; t1 += e1 * xs.y; t2 += e2 * xs.z; t3 += e3 * xs.w;
    }
#pragma unroll
    for (int off = 32; off > 0; off >>= 1) {
        d0 += __shfl_xor(d0, off); d1 += __shfl_xor(d1, off);
        d2 += __shfl_xor(d2, off); d3 += __shfl_xor(d3, off);
        t0 += __shfl_xor(t0, off); t1 += __shfl_xor(t1, off);
        t2 += __shfl_xor(t2, off); t3 += __shfl_xor(t3, off);
    }
    if (lane == 0) {
        float r = 0.25f * (t0 / (d0 + 1e-16f) + t1 / (d1 + 1e-16f) +
                           t2 / (d2 + 1e-16f) + t3 / (d3 + 1e-16f));
        out[n] = r + cb2[0] + LIN2[n];
    }
}

// ---------------- launch ----------------

extern "C" void kernel_launch(void* const* d_in, const int* in_sizes, int n_in,
                              void* d_out, int out_size, void* d_ws, size_t ws_size,
                              hipStream_t stream) {
    const float* x    = (const float*)d_in[0];
    const int*   ei   = (const int*)d_in[1];
    const float* cW0  = (const float*)d_in[3];
    const float* cas0 = (const float*)d_in[4];
    const float* cad0 = (const float*)d_in[5];
    const float* cb0  = (const float*)d_in[6];
    const float* lW0  = (const float*)d_in[7];
    const float* lb0  = (const float*)d_in[8];
    const float* cW1  = (const float*)d_in[9];
    const float* cas1 = (const float*)d_in[10];
    const float* cad1 = (const float*)d_in[11];
    const float* cb1  = (const float*)d_in[12];
    const float* lW1  = (const float*)d_in[13];
    const float* lb1  = (const float*)d_in[14];
    const float* cW2  = (const float*)d_in[15];
    const float* cas2 = (const float*)d_in[16];
    const float* cad2 = (const float*)d_in[17];
    const float* cb2  = (const float*)d_in[18];
    const float* lW2  = (const float*)d_in[19];
    const float* lb2  = (const float*)d_in[20];
    float* out = (float*)d_out;

    // workspace layout (~97 MB)
    short* xb    = (short*)d_ws;                 // 6.4M bf16
    short* XLb   = xb + 6400000;                 // 12.8M bf16
    short* HAb   = XLb + 12800000;
    short* Hlinb = HAb + 12800000;               // 12.8M bf16
    short* Wt0   = Hlinb + 12800000;             // 512*128
    short* Wt1   = Wt0 + 65536;                  // 512*256
    float* AS    = (float*)(Wt1 + 131072);
    float* AD    = AS + 200000;
    float* XL2   = AD + 200000;
    float* LIN2  = XL2 + 200000;
    int* deg     = (int*)(LIN2 + NN);            // [NN]
    int* cursor  = deg + NN;                     // [NN]
    int* gcnt    = cursor + NN;                  // [4]
    int* rowptr  = gcnt + 4;                     // [NN]
    int* csr_src = rowptr + NN;                  // [ET_]

    dim3 b256(256);
    dim3 gEdges((ET_ + 255) / 256);
    dim3 gNodesWave((NN + 3) / 4);

    // CSR build: zero deg+cursor+gcnt in one memset (contiguous)
    hipMemsetAsync(deg, 0, (2 * (size_t)NN + 4) * sizeof(int), stream);
    prep_all<<<dim3(7018), b256, 0, stream>>>(x, cW0, lW0, cW1, lW1, xb, Wt0, Wt1);
    degree_k<<<gEdges, b256, 0, stream>>>(ei, deg);
    alloc_scan<<<dim3((NN + 1023) / 1024), dim3(1024), 0, stream>>>(deg, rowptr, gcnt, NN);
    scatter_k<<<gEdges, b256, 0, stream>>>(ei, rowptr, cursor, csr_src);

    dim3 gemmGrid((NN + 127) / 128, 4);

    // layer 0
    gemm_bf16<<<gemmGrid, b256, 0, stream>>>(xb, Wt0, lb0, XLb, Hlinb, NN, 128);
    attn_prep<<<gNodesWave, b256, 0, stream>>>(XLb, cas0, cad0, AS, AD, NN);
    gat_agg<<<gNodesWave, b256, 0, stream>>>(XLb, AS, AD, rowptr, deg, csr_src, cb0, Hlinb,
                                             HAb, nullptr, nullptr, nullptr, nullptr, nullptr, NN);

    // layer 1 (+ fused layer-2 projections)
    gemm_bf16<<<gemmGrid, b256, 0, stream>>>(HAb, Wt1, lb1, XLb, Hlinb, NN, 256);
    attn_prep<<<gNodesWave, b256, 0, stream>>>(XLb, cas1, cad1, AS, AD, NN);
    gat_agg<<<gNodesWave, b256, 0, stream>>>(XLb, AS, AD, rowptr, deg, csr_src, cb1, Hlinb,
                                             nullptr, cW2, lW2, lb2, XL2, LIN2, NN);

    // layer 2 aggregation
    l2_agg<<<gNodesWave, b256, 0, stream>>>(XL2, LIN2, cas2, cad2, cb2, rowptr, deg, csr_src, out, NN);
}

// Round 7
// 462.210 us; speedup vs baseline: 2.0308x; 1.0968x over previous
//
#include <hip/hip_runtime.h>
#include <cstddef>
#include <cstdint>

#define NN 50000
#define EE 800000
#define ET_ (EE + NN)

typedef __attribute__((ext_vector_type(8))) short bf16x8;
typedef __attribute__((ext_vector_type(4))) float f32x4;

__device__ __forceinline__ float lrelu_(float x) { return x > 0.f ? x : 0.2f * x; }
__device__ __forceinline__ float elu_(float x)   { return x > 0.f ? x : (__expf(x) - 1.f); }
__device__ __forceinline__ short f2bf(float f) {
    unsigned u = __float_as_uint(f);
    unsigned r = (u + 0x7fffu + ((u >> 16) & 1u)) >> 16;
    return (short)r;
}
__device__ __forceinline__ float bflo(unsigned u) { return __uint_as_float(u << 16); }
__device__ __forceinline__ float bfhi(unsigned u) { return __uint_as_float(u & 0xffff0000u); }

#define GL16(gp, lp) __builtin_amdgcn_global_load_lds( \
    (const __attribute__((address_space(1))) unsigned int*)(gp), \
    (__attribute__((address_space(3))) unsigned int*)(lp), 16, 0, 0)

// ---------------- fused prep: x->bf16, pack Wt0/Wt1, degree histogram ----------------

__global__ __launch_bounds__(256) void prep_all(const float* __restrict__ x,
                                                const float* __restrict__ cW0, const float* __restrict__ lW0,
                                                const float* __restrict__ cW1, const float* __restrict__ lW1,
                                                const int* __restrict__ ei, int* __restrict__ deg,
                                                short* __restrict__ xb, short* __restrict__ Wt0,
                                                short* __restrict__ Wt1) {
    int i = blockIdx.x * 256 + threadIdx.x;
    if (i < 1600000) {
        float4 v = *(const float4*)(x + (size_t)i * 4);
        short4 o;
        o.x = f2bf(v.x); o.y = f2bf(v.y); o.z = f2bf(v.z); o.w = f2bf(v.w);
        *(short4*)(xb + (size_t)i * 4) = o;
        return;
    }
    i -= 1600000;
    if (i < 512 * 128) {
        int n = i >> 7, k = i & 127;
        float v = (n < 256) ? cW0[k * 256 + n] : lW0[k * 256 + (n - 256)];
        Wt0[i] = f2bf(v);
        return;
    }
    i -= 512 * 128;
    if (i < 512 * 256) {
        int n = i >> 8, k = i & 255;
        float v = (n < 256) ? cW1[k * 256 + n] : lW1[k * 256 + (n - 256)];
        Wt1[i] = f2bf(v);
        return;
    }
    i -= 512 * 256;
    if (i < ET_) {
        int d = (i < EE) ? ei[EE + i] : (i - EE);
        atomicAdd(&deg[d], 1);
    }
}

// ---------------- CSR build ----------------

__global__ __launch_bounds__(1024) void alloc_scan(const int* __restrict__ deg, int* __restrict__ rowptr,
                                                   int* __restrict__ gcnt, int n) {
    __shared__ int s[1024];
    __shared__ int basesh;
    int tid = threadIdx.x;
    int gid = blockIdx.x * 1024 + tid;
    int v = (gid < n) ? deg[gid] : 0;
    s[tid] = v;
    __syncthreads();
    for (int off = 1; off < 1024; off <<= 1) {
        int t = (tid >= off) ? s[tid - off] : 0;
        __syncthreads();
        s[tid] += t;
        __syncthreads();
    }
    if (tid == 1023) basesh = atomicAdd(gcnt, s[1023]);
    __syncthreads();
    if (gid < n) rowptr[gid] = basesh + s[tid] - v;
}

__global__ __launch_bounds__(256) void scatter_k(const int* __restrict__ ei,
                                                 const int* __restrict__ rowptr,
                                                 int* __restrict__ cursor,
                                                 int* __restrict__ csr_src) {
    int e = blockIdx.x * blockDim.x + threadIdx.x;
    if (e >= ET_) return;
    int s, d;
    if (e < EE) { s = ei[e]; d = ei[EE + e]; } else { s = e - EE; d = e - EE; }
    int pos = atomicAdd(&cursor[d], 1);
    csr_src[rowptr[d] + pos] = s;
}

// ---------------- bf16 MFMA GEMM, dbuf + LDS-staged epilogue ----------------
// out[M,512] = A[M,K] @ Wt^T ; cols<256 -> XLb, cols>=256 -> Hlinb (+biasLin)

__global__ __launch_bounds__(256) void gemm_bf16(const short* __restrict__ A,
                                                 const short* __restrict__ Wt,
                                                 const float* __restrict__ biasLin,
                                                 short* __restrict__ XLb,
                                                 short* __restrict__ Hlinb,
                                                 int M, int K) {
    __shared__ short smem[4][128 * 32];     // As0|As1|Bs0|Bs1, aliased as C-tile after loop
    const int tid = threadIdx.x;
    const int lane = tid & 63;
    const int wid = tid >> 6;
    const int bm = blockIdx.x * 128;
    const int col0 = blockIdx.y * 128;
    const int wr = wid >> 1, wc = wid & 1;

    f32x4 acc[4][4];
#pragma unroll
    for (int i = 0; i < 4; ++i)
#pragma unroll
        for (int j = 0; j < 4; ++j) acc[i][j] = (f32x4){0.f, 0.f, 0.f, 0.f};

    const int lrow = lane & 15, lk = lane >> 4;

    auto stage = [&](int b, int kk) {
#pragma unroll
        for (int it = 0; it < 2; ++it) {
            const int flat = tid + it * 256;
            const int row = flat >> 2, slot = flat & 3;
            const int ss = slot ^ (row & 3);      // pre-swizzled source chunk
            int ar = bm + row; ar = (ar < M) ? ar : (M - 1);
            GL16(A + (size_t)ar * K + kk + ss * 8, &smem[b][flat * 8]);
            GL16(Wt + (size_t)(col0 + row) * K + kk + ss * 8, &smem[2 + b][flat * 8]);
        }
    };

    stage(0, 0);
    int cur = 0;
    for (int k0 = 0; k0 < K; k0 += 32) {
        __syncthreads();
        if (k0 + 32 < K) stage(cur ^ 1, k0 + 32);
        bf16x8 af[4], bfr[4];
#pragma unroll
        for (int mi = 0; mi < 4; ++mi) {
            const int r = wr * 64 + mi * 16 + lrow;
            af[mi] = *(const bf16x8*)(&smem[cur][(r * 4 + (lk ^ (r & 3))) * 8]);
        }
#pragma unroll
        for (int ni = 0; ni < 4; ++ni) {
            const int c = wc * 64 + ni * 16 + lrow;
            bfr[ni] = *(const bf16x8*)(&smem[2 + cur][(c * 4 + (lk ^ (c & 3))) * 8]);
        }
#pragma unroll
        for (int mi = 0; mi < 4; ++mi)
#pragma unroll
            for (int ni = 0; ni < 4; ++ni)
                acc[mi][ni] = __builtin_amdgcn_mfma_f32_16x16x32_bf16(af[mi], bfr[ni], acc[mi][ni], 0, 0, 0);
        cur ^= 1;
    }

    __syncthreads();                        // all fragment ds_reads done -> reuse smem as C-tile
    short* Ct = &smem[0][0];                // [128][128] bf16, XOR-swizzled on bits 4-5
    const bool isLin = (col0 >= 256);
    float bni[4] = {0.f, 0.f, 0.f, 0.f};
    if (isLin) {
#pragma unroll
        for (int ni = 0; ni < 4; ++ni)
            bni[ni] = biasLin[col0 - 256 + wc * 64 + ni * 16 + lrow];
    }
    const int lrow4 = lk * 4;
#pragma unroll
    for (int mi = 0; mi < 4; ++mi) {
#pragma unroll
        for (int ni = 0; ni < 4; ++ni) {
            const int col_l = wc * 64 + ni * 16 + lrow;
#pragma unroll
            for (int rr = 0; rr < 4; ++rr) {
                const int row_l = wr * 64 + mi * 16 + lrow4 + rr;
                const int idx = (row_l * 128 + col_l) ^ (((row_l >> 2) & 3) << 4);
                Ct[idx] = f2bf(acc[mi][ni][rr] + bni[ni]);
            }
        }
    }
    __syncthreads();

    short* outp = isLin ? Hlinb : XLb;
    const int gcol0 = isLin ? (col0 - 256) : col0;
#pragma unroll
    for (int rr8 = 0; rr8 < 8; ++rr8) {
        const int flat = tid + rr8 * 256;
        const int row = flat >> 4, seg = flat & 15;
        const int sidx = (row * 128 + seg * 8) ^ (((row >> 2) & 3) << 4);
        if (bm + row < M) {
            bf16x8 vv = *(const bf16x8*)(Ct + sidx);
            *(bf16x8*)(outp + (size_t)(bm + row) * 256 + gcol0 + seg * 8) = vv;
        }
    }
}

// ---------------- attention prep: a_s/a_d per node per head ----------------

__global__ __launch_bounds__(256) void attn_prep(const short* __restrict__ XLb,
                                                 const float* __restrict__ cas,
                                                 const float* __restrict__ cad,
                                                 float* __restrict__ AS,
                                                 float* __restrict__ AD, int n_nodes) {
    int n = (blockIdx.x * blockDim.x + threadIdx.x) >> 6;
    int lane = threadIdx.x & 63;
    if (n >= n_nodes) return;
    uint2 q = *(const uint2*)(XLb + (size_t)n * 256 + lane * 4);
    float x0 = bflo(q.x), x1 = bfhi(q.x);
    float x2 = bflo(q.y), x3 = bfhi(q.y);
    float4 sv = *(const float4*)(cas + lane * 4);
    float4 dv = *(const float4*)(cad + lane * 4);
    float ps = x0 * sv.x + x1 * sv.y + x2 * sv.z + x3 * sv.w;
    float pd = x0 * dv.x + x1 * dv.y + x2 * dv.z + x3 * dv.w;
#pragma unroll
    for (int off = 1; off < 16; off <<= 1) {
        ps += __shfl_xor(ps, off);
        pd += __shfl_xor(pd, off);
    }
    if ((lane & 15) == 0) {
        AS[n * 4 + (lane >> 4)] = ps;
        AD[n * 4 + (lane >> 4)] = pd;
    }
}

// ---------------- GAT aggregation: wave per node, lane per edge, 4x-unrolled gather ----------------

__global__ __launch_bounds__(256) void gat_agg(const short* __restrict__ XLb,
                                               const float* __restrict__ AS,
                                               const float* __restrict__ AD,
                                               const int* __restrict__ rowptr,
                                               const int* __restrict__ degarr,
                                               const int* __restrict__ csr_src,
                                               const float* __restrict__ cb,
                                               const short* __restrict__ Hlinb,
                                               short* __restrict__ Hb,
                                               const float* __restrict__ cW2,
                                               const float* __restrict__ lW2,
                                               const float* __restrict__ lb2,
                                               float* __restrict__ XL2,
                                               float* __restrict__ LIN2,
                                               int n_nodes) {
    __shared__ int   sIdx[4][64];
    __shared__ float sExT[4][4][72];           // [wave][head][edge] padded

    const int tid = threadIdx.x;
    const int lane = tid & 63;
    const int w = tid >> 6;
    const int n = blockIdx.x * 4 + w;
    if (n >= n_nodes) return;                  // no block-level sync in this kernel

    const int rs = rowptr[n];
    const int deg = degarr[n];
    const float4 ad4 = *(const float4*)(AD + n * 4);

    const int half = lane >> 5;
    const int l32 = lane & 31;
    const int ch0 = l32 * 8;
    const int h = l32 >> 3;

    float4 acc0 = make_float4(0.f, 0.f, 0.f, 0.f);
    float4 acc1 = make_float4(0.f, 0.f, 0.f, 0.f);
    float d0 = 0.f, d1 = 0.f, d2 = 0.f, d3 = 0.f;

    auto ACC = [&](const uint4& q, float e) {
        acc0.x += e * bflo(q.x); acc0.y += e * bfhi(q.x);
        acc0.z += e * bflo(q.y); acc0.w += e * bfhi(q.y);
        acc1.x += e * bflo(q.z); acc1.y += e * bfhi(q.z);
        acc1.z += e * bflo(q.w); acc1.w += e * bfhi(q.w);
    };

    if (deg <= 64) {
        // fast path: scores lane-parallel, stay in registers across max+exp
        int sv = 0;
        float c0 = -1e30f, c1 = -1e30f, c2 = -1e30f, c3 = -1e30f;
        if (lane < deg) {
            sv = csr_src[rs + lane];
            float4 a = *(const float4*)(AS + sv * 4);
            c0 = lrelu_(a.x + ad4.x); c1 = lrelu_(a.y + ad4.y);
            c2 = lrelu_(a.z + ad4.z); c3 = lrelu_(a.w + ad4.w);
        }
        float m0 = c0, m1 = c1, m2 = c2, m3 = c3;
#pragma unroll
        for (int off = 32; off > 0; off >>= 1) {
            m0 = fmaxf(m0, __shfl_xor(m0, off));
            m1 = fmaxf(m1, __shfl_xor(m1, off));
            m2 = fmaxf(m2, __shfl_xor(m2, off));
            m3 = fmaxf(m3, __shfl_xor(m3, off));
        }
        float e0 = 0.f, e1 = 0.f, e2 = 0.f, e3 = 0.f;
        if (lane < deg) {
            e0 = __expf(c0 - m0); e1 = __expf(c1 - m1);
            e2 = __expf(c2 - m2); e3 = __expf(c3 - m3);
        }
        sIdx[w][lane] = sv;
        sExT[w][0][lane] = e0; sExT[w][1][lane] = e1;
        sExT[w][2][lane] = e2; sExT[w][3][lane] = e3;
        d0 = e0; d1 = e1; d2 = e2; d3 = e3;
        __builtin_amdgcn_wave_barrier();

        const int cpad = (deg + 1) & ~1;
        int j = 0;
        for (; j + 8 <= cpad; j += 8) {        // 8 edges / iter -> 4 independent 1KB gathers
            int ja = j + half, jb = j + 2 + half, jc = j + 4 + half, jd = j + 6 + half;
            int sa = sIdx[w][ja], sb = sIdx[w][jb], sc = sIdx[w][jc], sd = sIdx[w][jd];
            float ea = sExT[w][h][ja], eb = sExT[w][h][jb];
            float ec = sExT[w][h][jc], ed = sExT[w][h][jd];
            uint4 qa = *(const uint4*)(XLb + (size_t)sa * 256 + ch0);
            uint4 qb = *(const uint4*)(XLb + (size_t)sb * 256 + ch0);
            uint4 qc = *(const uint4*)(XLb + (size_t)sc * 256 + ch0);
            uint4 qd = *(const uint4*)(XLb + (size_t)sd * 256 + ch0);
            ACC(qa, ea); ACC(qb, eb); ACC(qc, ec); ACC(qd, ed);
        }
        for (; j < cpad; j += 2) {
            int jj = j + half;
            int s = sIdx[w][jj];
            float e = sExT[w][h][jj];
            uint4 q = *(const uint4*)(XLb + (size_t)s * 256 + ch0);
            ACC(q, e);
        }
    } else {
        // generic chunked path (statistically never taken at deg~Poisson(17))
        float m0 = -1e30f, m1 = -1e30f, m2 = -1e30f, m3 = -1e30f;
        for (int base = 0; base < deg; base += 64) {
            int idx = base + lane;
            if (idx < deg) {
                int s = csr_src[rs + idx];
                float4 a = *(const float4*)(AS + s * 4);
                m0 = fmaxf(m0, lrelu_(a.x + ad4.x));
                m1 = fmaxf(m1, lrelu_(a.y + ad4.y));
                m2 = fmaxf(m2, lrelu_(a.z + ad4.z));
                m3 = fmaxf(m3, lrelu_(a.w + ad4.w));
            }
        }
#pragma unroll
        for (int off = 32; off > 0; off >>= 1) {
            m0 = fmaxf(m0, __shfl_xor(m0, off));
            m1 = fmaxf(m1, __shfl_xor(m1, off));
            m2 = fmaxf(m2, __shfl_xor(m2, off));
            m3 = fmaxf(m3, __shfl_xor(m3, off));
        }
        for (int base = 0; base < deg; base += 64) {
            int cnt = deg - base; if (cnt > 64) cnt = 64;
            int idx = base + lane;
            int sv = 0;
            float e0 = 0.f, e1 = 0.f, e2 = 0.f, e3 = 0.f;
            if (idx < deg) {
                sv = csr_src[rs + idx];
                float4 a = *(const float4*)(AS + sv * 4);
                e0 = __expf(lrelu_(a.x + ad4.x) - m0);
                e1 = __expf(lrelu_(a.y + ad4.y) - m1);
                e2 = __expf(lrelu_(a.z + ad4.z) - m2);
                e3 = __expf(lrelu_(a.w + ad4.w) - m3);
            }
            sIdx[w][lane] = sv;
            sExT[w][0][lane] = e0; sExT[w][1][lane] = e1;
            sExT[w][2][lane] = e2; sExT[w][3][lane] = e3;
            d0 += e0; d1 += e1; d2 += e2; d3 += e3;
            __builtin_amdgcn_wave_barrier();
            int cpad = (cnt + 1) & ~1;
            for (int j = 0; j < cpad; j += 2) {
                int jj = j + half;
                int s = sIdx[w][jj];
                float e = sExT[w][h][jj];
                uint4 q = *(const uint4*)(XLb + (size_t)s * 256 + ch0);
                ACC(q, e);
            }
            __builtin_amdgcn_wave_barrier();
        }
    }

    // fold edge-halves + reduce denominators
    acc0.x += __shfl_xor(acc0.x, 32); acc0.y += __shfl_xor(acc0.y, 32);
    acc0.z += __shfl_xor(acc0.z, 32); acc0.w += __shfl_xor(acc0.w, 32);
    acc1.x += __shfl_xor(acc1.x, 32); acc1.y += __shfl_xor(acc1.y, 32);
    acc1.z += __shfl_xor(acc1.z, 32); acc1.w += __shfl_xor(acc1.w, 32);
#pragma unroll
    for (int off = 32; off > 0; off >>= 1) {
        d0 += __shfl_xor(d0, off); d1 += __shfl_xor(d1, off);
        d2 += __shfl_xor(d2, off); d3 += __shfl_xor(d3, off);
    }
    float den = (h == 0) ? d0 : (h == 1) ? d1 : (h == 2) ? d2 : d3;
    float inv = 1.f / (den + 1e-16f);

    float v0 = 0.f, v1 = 0.f, v2 = 0.f, v3 = 0.f, v4 = 0.f, v5 = 0.f, v6 = 0.f, v7 = 0.f;
    if (lane < 32) {
        size_t o = (size_t)n * 256 + ch0;
        uint4 hq = *(const uint4*)(Hlinb + o);
        float4 cba = *(const float4*)(cb + ch0);
        float4 cbb = *(const float4*)(cb + ch0 + 4);
        v0 = elu_(acc0.x * inv + cba.x + bflo(hq.x));
        v1 = elu_(acc0.y * inv + cba.y + bfhi(hq.x));
        v2 = elu_(acc0.z * inv + cba.z + bflo(hq.y));
        v3 = elu_(acc0.w * inv + cba.w + bfhi(hq.y));
        v4 = elu_(acc1.x * inv + cbb.x + bflo(hq.z));
        v5 = elu_(acc1.y * inv + cbb.y + bfhi(hq.z));
        v6 = elu_(acc1.z * inv + cbb.z + bflo(hq.w));
        v7 = elu_(acc1.w * inv + cbb.w + bfhi(hq.w));
    }

    if (XL2 != nullptr) {
        float p0 = 0.f, p1 = 0.f, p2 = 0.f, p3 = 0.f, pl = 0.f;
        if (lane < 32) {
            const float vv[8] = {v0, v1, v2, v3, v4, v5, v6, v7};
            float4 lwa = *(const float4*)(lW2 + ch0);
            float4 lwb = *(const float4*)(lW2 + ch0 + 4);
            const float lw[8] = {lwa.x, lwa.y, lwa.z, lwa.w, lwb.x, lwb.y, lwb.z, lwb.w};
#pragma unroll
            for (int j = 0; j < 8; ++j) {
                float4 wv = *(const float4*)(cW2 + (ch0 + j) * 4);
                p0 += vv[j] * wv.x; p1 += vv[j] * wv.y;
                p2 += vv[j] * wv.z; p3 += vv[j] * wv.w;
                pl += vv[j] * lw[j];
            }
        }
#pragma unroll
        for (int off = 16; off > 0; off >>= 1) {
            p0 += __shfl_xor(p0, off); p1 += __shfl_xor(p1, off);
            p2 += __shfl_xor(p2, off); p3 += __shfl_xor(p3, off);
            pl += __shfl_xor(pl, off);
        }
        if (lane == 0) {
            *(float4*)(XL2 + n * 4) = make_float4(p0, p1, p2, p3);
            LIN2[n] = pl + lb2[0];
        }
    } else if (lane < 32) {
        size_t o = (size_t)n * 256 + ch0;
        uint4 ov;
        ov.x = (unsigned)(unsigned short)f2bf(v0) | ((unsigned)(unsigned short)f2bf(v1) << 16);
        ov.y = (unsigned)(unsigned short)f2bf(v2) | ((unsigned)(unsigned short)f2bf(v3) << 16);
        ov.z = (unsigned)(unsigned short)f2bf(v4) | ((unsigned)(unsigned short)f2bf(v5) << 16);
        ov.w = (unsigned)(unsigned short)f2bf(v6) | ((unsigned)(unsigned short)f2bf(v7) << 16);
        *(uint4*)(Hb + o) = ov;
    }
}

// ---------------- layer 2 aggregation ----------------

__global__ __launch_bounds__(256) void l2_agg(const float* __restrict__ XL2,
                                              const float* __restrict__ LIN2,
                                              const float* __restrict__ cas2,
                                              const float* __restrict__ cad2,
                                              const float* __restrict__ cb2,
                                              const int* __restrict__ rowptr,
                                              const int* __restrict__ degarr,
                                              const int* __restrict__ csr_src,
                                              float* __restrict__ out, int n_nodes) {
    int n = (blockIdx.x * blockDim.x + threadIdx.x) >> 6;
    int lane = threadIdx.x & 63;
    if (n >= n_nodes) return;
    int rs = rowptr[n], re = rs + degarr[n];
    float4 xn = *(const float4*)(XL2 + n * 4);
    float cs0 = cas2[0], cs1 = cas2[1], cs2 = cas2[2], cs3 = cas2[3];
    float cd0 = cad2[0], cd1 = cad2[1], cd2 = cad2[2], cd3 = cad2[3];
    float ad0 = xn.x * cd0, ad1 = xn.y * cd1, ad2 = xn.z * cd2, ad3 = xn.w * cd3;

    float m0 = -1e30f, m1 = -1e30f, m2 = -1e30f, m3 = -1e30f;
    for (int i = rs + lane; i < re; i += 64) {
        int s = csr_src[i];
        float4 xs = *(const float4*)(XL2 + s * 4);
        m0 = fmaxf(m0, lrelu_(xs.x * cs0 + ad0));
        m1 = fmaxf(m1, lrelu_(xs.y * cs1 + ad1));
        m2 = fmaxf(m2, lrelu_(xs.z * cs2 + ad2));
        m3 = fmaxf(m3, lrelu_(xs.w * cs3 + ad3));
    }
#pragma unroll
    for (int off = 32; off > 0; off >>= 1) {
        m0 = fmaxf(m0, __shfl_xor(m0, off));
        m1 = fmaxf(m1, __shfl_xor(m1, off));
        m2 = fmaxf(m2, __shfl_xor(m2, off));
        m3 = fmaxf(m3, __shfl_xor(m3, off));
    }

    float d0 = 0.f, d1 = 0.f, d2 = 0.f, d3 = 0.f;
    float t0 = 0.f, t1 = 0.f, t2 = 0.f, t3 = 0.f;
    for (int i = rs + lane; i < re; i += 64) {
        int s = csr_src[i];
        float4 xs = *(const float4*)(XL2 + s * 4);
        float e0 = __expf(lrelu_(xs.x * cs0 + ad0) - m0);
        float e1 = __expf(lrelu_(xs.y * cs1 + ad1) - m1);
        float e2 = __expf(lrelu_(xs.z * cs2 + ad2) - m2);
        float e3 = __expf(lrelu_(xs.w * cs3 + ad3) - m3);
        d0 += e0; d1 += e1; d2 += e2; d3 += e3;
        t0 += e0 * xs.x; t1 += e1 * xs.y; t2 += e2 * xs.z; t3 += e3 * xs.w;
    }
#pragma unroll
    for (int off = 32; off > 0; off >>= 1) {
        d0 += __shfl_xor(d0, off); d1 += __shfl_xor(d1, off);
        d2 += __shfl_xor(d2, off); d3 += __shfl_xor(d3, off);
        t0 += __shfl_xor(t0, off); t1 += __shfl_xor(t1, off);
        t2 += __shfl_xor(t2, off); t3 += __shfl_xor(t3, off);
    }
    if (lane == 0) {
        float r = 0.25f * (t0 / (d0 + 1e-16f) + t1 / (d1 + 1e-16f) +
                           t2 / (d2 + 1e-16f) + t3 / (d3 + 1e-16f));
        out[n] = r + cb2[0] + LIN2[n];
    }
}

// ---------------- launch ----------------

extern "C" void kernel_launch(void* const* d_in, const int* in_sizes, int n_in,
                              void* d_out, int out_size, void* d_ws, size_t ws_size,
                              hipStream_t stream) {
    const float* x    = (const float*)d_in[0];
    const int*   ei   = (const int*)d_in[1];
    const float* cW0  = (const float*)d_in[3];
    const float* cas0 = (const float*)d_in[4];
    const float* cad0 = (const float*)d_in[5];
    const float* cb0  = (const float*)d_in[6];
    const float* lW0  = (const float*)d_in[7];
    const float* lb0  = (const float*)d_in[8];
    const float* cW1  = (const float*)d_in[9];
    const float* cas1 = (const float*)d_in[10];
    const float* cad1 = (const float*)d_in[11];
    const float* cb1  = (const float*)d_in[12];
    const float* lW1  = (const float*)d_in[13];
    const float* lb1  = (const float*)d_in[14];
    const float* cW2  = (const float*)d_in[15];
    const float* cas2 = (const float*)d_in[16];
    const float* cad2 = (const float*)d_in[17];
    const float* cb2  = (const float*)d_in[18];
    const float* lW2  = (const float*)d_in[19];
    const float* lb2  = (const float*)d_in[20];
    float* out = (float*)d_out;

    // workspace layout (~97 MB)
    short* xb    = (short*)d_ws;                 // 6.4M bf16
    short* XLb   = xb + 6400000;                 // 12.8M bf16
    short* HAb   = XLb + 12800000;
    short* Hlinb = HAb + 12800000;               // 12.8M bf16
    short* Wt0   = Hlinb + 12800000;             // 512*128
    short* Wt1   = Wt0 + 65536;                  // 512*256
    float* AS    = (float*)(Wt1 + 131072);
    float* AD    = AS + 200000;
    float* XL2   = AD + 200000;
    float* LIN2  = XL2 + 200000;
    int* deg     = (int*)(LIN2 + NN);            // [NN]
    int* cursor  = deg + NN;                     // [NN]
    int* gcnt    = cursor + NN;                  // [4]
    int* rowptr  = gcnt + 4;                     // [NN]
    int* csr_src = rowptr + NN;                  // [ET_]

    dim3 b256(256);
    dim3 gEdges((ET_ + 255) / 256);
    dim3 gNodesWave((NN + 3) / 4);

    // zero deg+cursor+gcnt in one memset (contiguous)
    hipMemsetAsync(deg, 0, (2 * (size_t)NN + 4) * sizeof(int), stream);
    prep_all<<<dim3(10339), b256, 0, stream>>>(x, cW0, lW0, cW1, lW1, ei, deg, xb, Wt0, Wt1);
    alloc_scan<<<dim3((NN + 1023) / 1024), dim3(1024), 0, stream>>>(deg, rowptr, gcnt, NN);
    scatter_k<<<gEdges, b256, 0, stream>>>(ei, rowptr, cursor, csr_src);

    dim3 gemmGrid((NN + 127) / 128, 4);

    // layer 0
    gemm_bf16<<<gemmGrid, b256, 0, stream>>>(xb, Wt0, lb0, XLb, Hlinb, NN, 128);
    attn_prep<<<gNodesWave, b256, 0, stream>>>(XLb, cas0, cad0, AS, AD, NN);
    gat_agg<<<gNodesWave, b256, 0, stream>>>(XLb, AS, AD, rowptr, deg, csr_src, cb0, Hlinb,
                                             HAb, nullptr, nullptr, nullptr, nullptr, nullptr, NN);

    // layer 1 (+ fused layer-2 projections)
    gemm_bf16<<<gemmGrid, b256, 0, stream>>>(HAb, Wt1, lb1, XLb, Hlinb, NN, 256);
    attn_prep<<<gNodesWave, b256, 0, stream>>>(XLb, cas1, cad1, AS, AD, NN);
    gat_agg<<<gNodesWave, b256, 0, stream>>>(XLb, AS, AD, rowptr, deg, csr_src, cb1, Hlinb,
                                             nullptr, cW2, lW2, lb2, XL2, LIN2, NN);

    // layer 2 aggregation
    l2_agg<<<gNodesWave, b256, 0, stream>>>(XL2, LIN2, cas2, cad2, cb2, rowptr, deg, csr_src, out, NN);
}